// Round 4
// baseline (699.149 us; speedup 1.0000x reference)
//
#include <hip/hip_runtime.h>
#include <hip/hip_fp16.h>
#include <math.h>

#define N_NODES 100000
#define IN_F 128
#define NF 16      // HEADS * OUT_C
#define HEADS 8
#define NEG_SLOPE 0.2f

#define RB 128          // nodes per bin (power of 2)
#define LOG_RB 7
#define NB 782          // ceil(100000/128)
#define SBITS 17        // src id bits (100000 < 2^17)
#define SMASK ((1u << SBITS) - 1)
#define BIN_C 8192      // edges per binning block

// ---------------------------------------------------------------------------
// Phase 1: h = x@W, attention logits. 16 lanes per node.
// Emits combined fp16 node record rec[n] (32 halves = 64B):
//   [0..7]=asrc f16, [8..23]=h f16, [24..31]=pad.  adst kept f32.
// ---------------------------------------------------------------------------
__global__ __launch_bounds__(256) void phase1_kernel(
    const float* __restrict__ x, const float* __restrict__ W,
    const float* __restrict__ att_src, const float* __restrict__ att_dst,
    __half* __restrict__ rec, float* __restrict__ adst)
{
    __shared__ float Ws[IN_F * NF];
    for (int i = threadIdx.x; i < IN_F * NF; i += 256) Ws[i] = W[i];
    __syncthreads();

    int tid  = blockIdx.x * 256 + threadIdx.x;
    int node = tid >> 4;
    int j    = tid & 15;
    if (node >= N_NODES) return;

    const float4* xr4 = (const float4*)(x + (size_t)node * IN_F);
    float acc = 0.f;
    #pragma unroll 8
    for (int k4 = 0; k4 < IN_F / 4; ++k4) {
        float4 xv = xr4[k4];
        acc = fmaf(xv.x, Ws[(4 * k4 + 0) * NF + j], acc);
        acc = fmaf(xv.y, Ws[(4 * k4 + 1) * NF + j], acc);
        acc = fmaf(xv.z, Ws[(4 * k4 + 2) * NF + j], acc);
        acc = fmaf(xv.w, Ws[(4 * k4 + 3) * NF + j], acc);
    }
    rec[(size_t)node * 32 + 8 + j] = __float2half(acc);

    int hd = j >> 1, c = j & 1;
    float vs = acc * att_src[hd * 2 + c];
    float vd = acc * att_dst[hd * 2 + c];
    vs += __shfl_xor(vs, 1);
    vd += __shfl_xor(vd, 1);
    if (c == 0) {
        rec[(size_t)node * 32 + hd] = __float2half(vs);
        adst[node * HEADS + hd] = vd;
    }
}

// ---------------------------------------------------------------------------
// Binning: counting-sort BIN_C-edge chunks by dst bin (dst >> LOG_RB) in LDS,
// reserve per-(block,bin) output ranges with ONE global atomic each, write
// packed records (d_local<<17 | src) coalesced into per-bin segments.
// ---------------------------------------------------------------------------
__global__ __launch_bounds__(256) void bin_kernel(
    const int* __restrict__ ei, int* __restrict__ bin_cursor,
    unsigned* __restrict__ bins, int E, int capb)
{
    __shared__ unsigned staging[BIN_C];
    __shared__ unsigned short bin16[BIN_C];
    __shared__ int hist[NB], offs[NB], cur[NB], gbase[NB];
    __shared__ int wsum[4], woff[4];

    int t = threadIdx.x;
    int base = blockIdx.x * BIN_C;
    int n_valid = E - base;
    if (n_valid > BIN_C) n_valid = BIN_C;
    if (n_valid < 0) n_valid = 0;

    for (int b = t; b < NB; b += 256) hist[b] = 0;
    __syncthreads();

    // A: histogram of dst bins
    for (int i = t; i < n_valid; i += 256)
        atomicAdd(&hist[ei[E + base + i] >> LOG_RB], 1);
    __syncthreads();

    // B: block-wide exclusive scan of hist (4 bins per thread) + global reserve
    int h4[4], sum = 0;
    #pragma unroll
    for (int k = 0; k < 4; ++k) {
        int b = 4 * t + k;
        h4[k] = (b < NB) ? hist[b] : 0;
        sum += h4[k];
    }
    int lane = t & 63, wid = t >> 6;
    int v = sum;
    #pragma unroll
    for (int o = 1; o < 64; o <<= 1) {
        int u = __shfl_up(v, o);
        if (lane >= o) v += u;
    }
    if (lane == 63) wsum[wid] = v;
    __syncthreads();
    if (t == 0) { int r = 0; for (int w = 0; w < 4; ++w) { woff[w] = r; r += wsum[w]; } }
    __syncthreads();
    int run = woff[wid] + v - sum;
    #pragma unroll
    for (int k = 0; k < 4; ++k) {
        int b = 4 * t + k;
        if (b < NB) { offs[b] = run; cur[b] = run; }
        run += h4[k];
    }
    __syncthreads();
    for (int b = t; b < NB; b += 256)
        gbase[b] = hist[b] ? atomicAdd(&bin_cursor[b], hist[b]) : 0;
    __syncthreads();

    // C: counting-sort into LDS staging
    for (int i = t; i < n_valid; i += 256) {
        int s = ei[base + i];
        int d = ei[E + base + i];
        int b = d >> LOG_RB;
        int slot = atomicAdd(&cur[b], 1);
        staging[slot] = ((unsigned)(d & (RB - 1)) << SBITS) | (unsigned)s;
        bin16[slot] = (unsigned short)b;
    }
    __syncthreads();

    // D: coalesced write-out (consecutive slots -> consecutive global positions)
    for (int i = t; i < n_valid; i += 256) {
        int b = bin16[i];
        int pos = gbase[b] + (i - offs[b]);
        if (pos < capb) bins[(size_t)b * capb + pos] = staging[i];
    }
}

// ---------------------------------------------------------------------------
// Accumulate + finalize: one block per bin. Per-node (den,num0,num1)x8 heads
// in LDS (stride 25 words, coprime with 32 banks). Per edge: ONE random 64B
// record gather + 24 LDS atomics. Then fused self-loop/normalize/bias/FC.
// ---------------------------------------------------------------------------
__global__ __launch_bounds__(512) void accum_kernel(
    const unsigned* __restrict__ bins, const int* __restrict__ bin_cursor,
    const __half* __restrict__ rec, const float* __restrict__ adst,
    const float* __restrict__ bias, const float* __restrict__ Wfc,
    const float* __restrict__ bfc, float* __restrict__ out, int capb)
{
    __shared__ float acc[RB * 25];     // 12.8 KB
    __shared__ float adst_s[RB * HEADS]; // 4 KB

    int t = threadIdx.x;
    int b = blockIdx.x;
    int node0 = b * RB;

    for (int i = t; i < RB * 25; i += 512) acc[i] = 0.f;
    for (int i = t; i < RB * HEADS; i += 512) {
        int n = node0 + (i >> 3);
        adst_s[i] = (n < N_NODES) ? adst[n * HEADS + (i & 7)] : 0.f;
    }
    __syncthreads();

    int cnt = bin_cursor[b];
    if (cnt > capb) cnt = capb;
    const unsigned* seg = bins + (size_t)b * capb;

    for (int i = t; i < cnt; i += 512) {
        unsigned r = seg[i];
        int s  = r & SMASK;
        int dl = r >> SBITS;
        const __half* rp = rec + (size_t)s * 32;
        float4 f0 = *(const float4*)(rp);        // asrc f16 x8
        float4 f1 = *(const float4*)(rp + 8);    // h f16 0..7
        float4 f2 = *(const float4*)(rp + 16);   // h f16 8..15
        const __half* ah  = (const __half*)&f0;
        const __half* hh0 = (const __half*)&f1;
        const __half* hh1 = (const __half*)&f2;
        float* accd = acc + dl * 25;
        const float* ad = adst_s + dl * HEADS;
        #pragma unroll
        for (int hd = 0; hd < HEADS; ++hd) {
            float l = __half2float(ah[hd]) + ad[hd];
            l = l > 0.f ? l : NEG_SLOPE * l;
            float p = __expf(l);
            const __half* hp = (hd < 4) ? hh0 : hh1;
            float h0 = __half2float(hp[(hd & 3) * 2]);
            float h1 = __half2float(hp[(hd & 3) * 2 + 1]);
            atomicAdd(accd + hd * 3 + 0, p);
            atomicAdd(accd + hd * 3 + 1, p * h0);
            atomicAdd(accd + hd * 3 + 2, p * h1);
        }
    }
    __syncthreads();

    // finalize the bin's nodes (self-loop folded analytically)
    if (t < RB) {
        int n = node0 + t;
        if (n < N_NODES) {
            const __half* rp = rec + (size_t)n * 32;
            const float* ad = adst_s + t * HEADS;
            float* accd = acc + t * 25;
            float o0 = bfc[0], o1 = bfc[1];
            #pragma unroll
            for (int hd = 0; hd < HEADS; ++hd) {
                float l = __half2float(rp[hd]) + ad[hd];
                l = l > 0.f ? l : NEG_SLOPE * l;
                float p = __expf(l);
                float h0 = __half2float(rp[8 + 2 * hd]);
                float h1 = __half2float(rp[8 + 2 * hd + 1]);
                float den = accd[hd * 3 + 0] + p;
                float n0  = accd[hd * 3 + 1] + p * h0;
                float n1  = accd[hd * 3 + 2] + p * h1;
                float g0 = n0 / den + bias[2 * hd];
                float g1 = n1 / den + bias[2 * hd + 1];
                o0 = fmaf(g0, Wfc[(2 * hd) * 2 + 0], o0);
                o0 = fmaf(g1, Wfc[(2 * hd + 1) * 2 + 0], o0);
                o1 = fmaf(g0, Wfc[(2 * hd) * 2 + 1], o1);
                o1 = fmaf(g1, Wfc[(2 * hd + 1) * 2 + 1], o1);
            }
            float2 res = { o0, o1 };
            *(float2*)(out + (size_t)n * 2) = res;
        }
    }
}

// ---------------------------------------------------------------------------
extern "C" void kernel_launch(void* const* d_in, const int* in_sizes, int n_in,
                              void* d_out, int out_size, void* d_ws, size_t ws_size,
                              hipStream_t stream)
{
    const float* x       = (const float*)d_in[0];
    const int*   ei      = (const int*)d_in[1];   // [2, E]
    const float* W       = (const float*)d_in[3];
    const float* att_src = (const float*)d_in[4];
    const float* att_dst = (const float*)d_in[5];
    const float* bias    = (const float*)d_in[6];
    const float* Wfc     = (const float*)d_in[7];
    const float* bfc     = (const float*)d_in[8];
    float*       out     = (float*)d_out;

    const int E = in_sizes[1] / 2;

    // per-bin segment capacity: mean + 8 sigma + slack, 16-aligned
    double lam = (double)E / NB * ((double)NB * RB / N_NODES); // mean per full bin
    int capb = (int)(lam + 8.0 * sqrt(lam) + 64.0);
    capb = (capb + 15) & ~15;

    // ws layout: rec f16[N*32] (6.4MB) | adst f32[N*8] (3.2MB) |
    //            bin_cursor i32[NB] | (4KB align) | bins u32[NB*capb] (~14.6MB)
    __half* rec        = (__half*)d_ws;
    float*  adst       = (float*)((char*)d_ws + (size_t)N_NODES * 32 * 2);
    int*    bin_cursor = (int*)((char*)adst + (size_t)N_NODES * HEADS * 4);
    size_t  bins_off   = (((size_t)((char*)bin_cursor - (char*)d_ws)) + NB * 4 + 4095) & ~(size_t)4095;
    unsigned* bins     = (unsigned*)((char*)d_ws + bins_off);

    hipMemsetAsync(bin_cursor, 0, NB * sizeof(int), stream);

    phase1_kernel<<<(N_NODES * 16 + 255) / 256, 256, 0, stream>>>(
        x, W, att_src, att_dst, rec, adst);
    bin_kernel<<<(E + BIN_C - 1) / BIN_C, 256, 0, stream>>>(
        ei, bin_cursor, bins, E, capb);
    accum_kernel<<<NB, 512, 0, stream>>>(
        bins, bin_cursor, rec, adst, bias, Wfc, bfc, out, capb);
}

// Round 5
// 245.121 us; speedup vs baseline: 2.8523x; 2.8523x over previous
//
#include <hip/hip_runtime.h>
#include <hip/hip_fp16.h>

#define N_NODES 100000
#define IN_F 128
#define NF 16      // HEADS * OUT_C
#define HEADS 8
#define NEG_SLOPE 0.2f

#define RB 128          // nodes per bin (power of 2)
#define LOG_RB 7
#define NB 782          // ceil(100000/128)
#define SBITS 17        // src id bits (100000 < 2^17)
#define SMASK ((1u << SBITS) - 1)
#define BIN_C 8192      // edges per binning block
#define CAPB 4672       // per-bin segment capacity: mean 4096 + 8*sigma + slack

// ---------------------------------------------------------------------------
// Phase 1: h = x@W, attention logits. 16 lanes per node.
// Emits combined fp16 node record rec[n] (32 halves = 64B, one cache line):
//   [0..7]=asrc f16, [8..23]=h f16, [24..31]=pad.  adst kept f32.
// ---------------------------------------------------------------------------
__global__ __launch_bounds__(256) void phase1_kernel(
    const float* __restrict__ x, const float* __restrict__ W,
    const float* __restrict__ att_src, const float* __restrict__ att_dst,
    __half* __restrict__ rec, float* __restrict__ adst)
{
    __shared__ float Ws[IN_F * NF];
    for (int i = threadIdx.x; i < IN_F * NF; i += 256) Ws[i] = W[i];
    __syncthreads();

    int tid  = blockIdx.x * 256 + threadIdx.x;
    int node = tid >> 4;
    int j    = tid & 15;
    if (node >= N_NODES) return;

    const float4* xr4 = (const float4*)(x + (size_t)node * IN_F);
    float acc = 0.f;
    #pragma unroll 8
    for (int k4 = 0; k4 < IN_F / 4; ++k4) {
        float4 xv = xr4[k4];
        acc = fmaf(xv.x, Ws[(4 * k4 + 0) * NF + j], acc);
        acc = fmaf(xv.y, Ws[(4 * k4 + 1) * NF + j], acc);
        acc = fmaf(xv.z, Ws[(4 * k4 + 2) * NF + j], acc);
        acc = fmaf(xv.w, Ws[(4 * k4 + 3) * NF + j], acc);
    }
    rec[(size_t)node * 32 + 8 + j] = __float2half(acc);

    int hd = j >> 1, c = j & 1;
    float vs = acc * att_src[hd * 2 + c];
    float vd = acc * att_dst[hd * 2 + c];
    vs += __shfl_xor(vs, 1);
    vd += __shfl_xor(vd, 1);
    if (c == 0) {
        rec[(size_t)node * 32 + hd] = __float2half(vs);
        adst[node * HEADS + hd] = vd;
    }
}

// ---------------------------------------------------------------------------
// Binning: counting-sort BIN_C-edge chunks by dst bin (dst >> LOG_RB) in LDS,
// reserve per-(block,bin) ranges with ONE global atomic each (~300k total),
// write packed records (d_local<<17 | src) coalesced into per-bin segments.
// ---------------------------------------------------------------------------
__global__ __launch_bounds__(256) void bin_kernel(
    const int* __restrict__ ei, int* __restrict__ bin_cursor,
    unsigned* __restrict__ bins, int E)
{
    __shared__ unsigned staging[BIN_C];
    __shared__ unsigned short bin16[BIN_C];
    __shared__ int hist[NB], offs[NB], cur[NB], gbase[NB];
    __shared__ int wsum[4], woff[4];

    int t = threadIdx.x;
    int base = blockIdx.x * BIN_C;
    int n_valid = E - base;
    if (n_valid > BIN_C) n_valid = BIN_C;
    if (n_valid < 0) n_valid = 0;

    for (int b = t; b < NB; b += 256) hist[b] = 0;
    __syncthreads();

    // A: histogram of dst bins
    for (int i = t; i < n_valid; i += 256)
        atomicAdd(&hist[ei[E + base + i] >> LOG_RB], 1);
    __syncthreads();

    // B: block-wide exclusive scan of hist (4 bins/thread) + global reserve
    int h4[4], sum = 0;
    #pragma unroll
    for (int k = 0; k < 4; ++k) {
        int b = 4 * t + k;
        h4[k] = (b < NB) ? hist[b] : 0;
        sum += h4[k];
    }
    int lane = t & 63, wid = t >> 6;
    int v = sum;
    #pragma unroll
    for (int o = 1; o < 64; o <<= 1) {
        int u = __shfl_up(v, o);
        if (lane >= o) v += u;
    }
    if (lane == 63) wsum[wid] = v;
    __syncthreads();
    if (t == 0) { int r = 0; for (int w = 0; w < 4; ++w) { woff[w] = r; r += wsum[w]; } }
    __syncthreads();
    int run = woff[wid] + v - sum;
    #pragma unroll
    for (int k = 0; k < 4; ++k) {
        int b = 4 * t + k;
        if (b < NB) { offs[b] = run; cur[b] = run; }
        run += h4[k];
    }
    __syncthreads();
    for (int b = t; b < NB; b += 256)
        gbase[b] = hist[b] ? atomicAdd(&bin_cursor[b], hist[b]) : 0;
    __syncthreads();

    // C: counting-sort into LDS staging
    for (int i = t; i < n_valid; i += 256) {
        int s = ei[base + i];
        int d = ei[E + base + i];
        int b = d >> LOG_RB;
        int slot = atomicAdd(&cur[b], 1);
        staging[slot] = ((unsigned)(d & (RB - 1)) << SBITS) | (unsigned)s;
        bin16[slot] = (unsigned short)b;
    }
    __syncthreads();

    // D: coalesced write-out (consecutive slots -> consecutive positions)
    for (int i = t; i < n_valid; i += 256) {
        int b = bin16[i];
        int pos = gbase[b] + (i - offs[b]);
        if (pos < CAPB) bins[(size_t)b * CAPB + pos] = staging[i];
    }
}

// ---------------------------------------------------------------------------
// Accum: one block (512 thr, 8 waves) per bin.
//  Phase A-C: LDS counting sort of the segment into per-node order
//             (2 LDS atomics per edge, no fp atomics anywhere).
//  Phase D:   wave-per-node register accumulation (round-3-proven structure):
//             lane = e_off(0..7) x head(0..7); ONE random 64B line per edge;
//             shuffle reduce; fused self-loop + normalize + bias + FC.
// ---------------------------------------------------------------------------
__global__ __launch_bounds__(512) void accum2_kernel(
    const unsigned* __restrict__ bins, const int* __restrict__ bin_cursor,
    const __half* __restrict__ rec, const float* __restrict__ adst,
    const float* __restrict__ bias, const float* __restrict__ Wfc,
    const float* __restrict__ bfc, float* __restrict__ out)
{
    __shared__ unsigned staging[CAPB];          // 18.7 KB
    __shared__ int hist[RB], offs[RB + 1], cur[RB];

    int t = threadIdx.x;
    int b = blockIdx.x;
    int node0 = b * RB;

    for (int i = t; i < RB; i += 512) hist[i] = 0;
    __syncthreads();

    int cnt = bin_cursor[b];
    if (cnt > CAPB) cnt = CAPB;
    const unsigned* seg = bins + (size_t)b * CAPB;

    // A: per-node histogram
    for (int i = t; i < cnt; i += 512)
        atomicAdd(&hist[seg[i] >> SBITS], 1);
    __syncthreads();

    // B: scan of 128 counters by wave 0 (lane l owns bins 2l, 2l+1)
    if (t < 64) {
        int h0 = hist[2 * t], h1 = hist[2 * t + 1];
        int v = h0 + h1;
        int inc = v;
        #pragma unroll
        for (int o = 1; o < 64; o <<= 1) {
            int u = __shfl_up(inc, o);
            if (t >= o) inc += u;
        }
        int ex = inc - v;
        offs[2 * t] = ex;       cur[2 * t] = ex;
        offs[2 * t + 1] = ex + h0; cur[2 * t + 1] = ex + h0;
        if (t == 63) offs[RB] = inc;
    }
    __syncthreads();

    // C: sort src ids into per-node order in LDS
    for (int i = t; i < cnt; i += 512) {
        unsigned r = seg[i];
        int slot = atomicAdd(&cur[r >> SBITS], 1);
        staging[slot] = r & SMASK;
    }
    __syncthreads();

    // D: wave-per-node gather
    int wv = t >> 6, lane = t & 63;
    int h_id = lane & 7, e_off = lane >> 3;

    for (int k = 0; k < RB / 8; ++k) {
        int dl = wv + 8 * k;            // wave-uniform
        int n = node0 + dl;
        if (n >= N_NODES) break;
        int st  = offs[dl];
        int deg = offs[dl + 1] - st;

        float adst_h = adst[n * HEADS + h_id];
        float den = 0.f, num0 = 0.f, num1 = 0.f;

        for (int i = e_off; i < deg; i += 8) {
            int s = staging[st + i];                    // LDS broadcast
            const __half* rp = rec + (size_t)s * 32;    // one 64B line
            float a = __half2float(rp[h_id]);
            __half2 hp = *(const __half2*)(rp + 8 + 2 * h_id);
            float l = a + adst_h;
            l = l > 0.f ? l : NEG_SLOPE * l;
            float p = __expf(l);
            den += p;
            num0 = fmaf(p, __half2float(hp.x), num0);
            num1 = fmaf(p, __half2float(hp.y), num1);
        }
        #pragma unroll
        for (int m = 8; m < 64; m <<= 1) {
            den  += __shfl_xor(den,  m);
            num0 += __shfl_xor(num0, m);
            num1 += __shfl_xor(num1, m);
        }
        // self-loop folded analytically
        {
            const __half* rp = rec + (size_t)n * 32;
            float a = __half2float(rp[h_id]);
            __half2 hp = *(const __half2*)(rp + 8 + 2 * h_id);
            float l = a + adst_h;
            l = l > 0.f ? l : NEG_SLOPE * l;
            float p = __expf(l);
            den += p;
            num0 = fmaf(p, __half2float(hp.x), num0);
            num1 = fmaf(p, __half2float(hp.y), num1);
        }
        // normalize + bias + FC, sum over heads
        float g0 = num0 / den + bias[2 * h_id];
        float g1 = num1 / den + bias[2 * h_id + 1];
        float o0 = g0 * Wfc[(2 * h_id) * 2 + 0] + g1 * Wfc[(2 * h_id + 1) * 2 + 0];
        float o1 = g0 * Wfc[(2 * h_id) * 2 + 1] + g1 * Wfc[(2 * h_id + 1) * 2 + 1];
        #pragma unroll
        for (int m = 1; m < 8; m <<= 1) {
            o0 += __shfl_xor(o0, m);
            o1 += __shfl_xor(o1, m);
        }
        if (lane == 0) {
            float2 res = { o0 + bfc[0], o1 + bfc[1] };
            *(float2*)(out + (size_t)n * 2) = res;
        }
    }
}

// ---------------------------------------------------------------------------
extern "C" void kernel_launch(void* const* d_in, const int* in_sizes, int n_in,
                              void* d_out, int out_size, void* d_ws, size_t ws_size,
                              hipStream_t stream)
{
    const float* x       = (const float*)d_in[0];
    const int*   ei      = (const int*)d_in[1];   // [2, E]
    const float* W       = (const float*)d_in[3];
    const float* att_src = (const float*)d_in[4];
    const float* att_dst = (const float*)d_in[5];
    const float* bias    = (const float*)d_in[6];
    const float* Wfc     = (const float*)d_in[7];
    const float* bfc     = (const float*)d_in[8];
    float*       out     = (float*)d_out;

    const int E = in_sizes[1] / 2;

    // ws layout: rec f16[N*32] (6.4MB) | adst f32[N*8] (3.2MB) |
    //            bin_cursor i32[NB] | (4KB align) | bins u32[NB*CAPB] (~14.6MB)
    __half* rec        = (__half*)d_ws;
    float*  adst       = (float*)((char*)d_ws + (size_t)N_NODES * 32 * 2);
    int*    bin_cursor = (int*)((char*)adst + (size_t)N_NODES * HEADS * 4);
    size_t  bins_off   = (((size_t)((char*)bin_cursor - (char*)d_ws)) + NB * 4 + 4095) & ~(size_t)4095;
    unsigned* bins     = (unsigned*)((char*)d_ws + bins_off);

    hipMemsetAsync(bin_cursor, 0, NB * sizeof(int), stream);

    phase1_kernel<<<(N_NODES * 16 + 255) / 256, 256, 0, stream>>>(
        x, W, att_src, att_dst, rec, adst);
    bin_kernel<<<(E + BIN_C - 1) / BIN_C, 256, 0, stream>>>(
        ei, bin_cursor, bins, E);
    accum2_kernel<<<NB, 512, 0, stream>>>(
        bins, bin_cursor, rec, adst, bias, Wfc, bfc, out);
}

// Round 6
// 237.184 us; speedup vs baseline: 2.9477x; 1.0335x over previous
//
#include <hip/hip_runtime.h>
#include <hip/hip_fp16.h>

#define N_NODES 100000
#define IN_F 128
#define NF 16      // HEADS * OUT_C
#define HEADS 8
#define NEG_SLOPE 0.2f
#define LOG2E 1.44269504f

#define RB 128          // nodes per bin (power of 2)
#define LOG_RB 7
#define NB 782          // ceil(100000/128)
#define SBITS 17        // src id bits (100000 < 2^17)
#define SMASK ((1u << SBITS) - 1)
#define BIN_C 8192      // edges per binning block
#define CAPB 4672       // per-bin segment capacity: mean 4096 + 8*sigma + slack
#define HCAP 2560       // half-bin LDS staging capacity (mean 2046 + >10 sigma)

// ---------------------------------------------------------------------------
// phase1 role: h = x@W, attention logits. 16 lanes per node, 512-thr blocks.
// Emits fp16 node record rec[n] (32 halves = 64B, one cache line):
//   [0..7]=asrc*log2e f16, [8..23]=h f16, [24..31]=pad.  adst (*log2e) f32.
// Logits pre-scaled by log2(e) so the consumer uses exp2 (leaky-relu commutes
// with positive scaling).
// ---------------------------------------------------------------------------
__device__ __forceinline__ void phase1_body(
    int pb, const float* __restrict__ x, const float* __restrict__ W,
    const float* __restrict__ att_src, const float* __restrict__ att_dst,
    __half* __restrict__ rec, float* __restrict__ adst, float* Ws)
{
    int t = threadIdx.x;
    for (int i = t; i < IN_F * NF; i += 512) Ws[i] = W[i];
    __syncthreads();

    int tid  = pb * 512 + t;
    int node = tid >> 4;
    int j    = tid & 15;
    if (node >= N_NODES) return;

    const float4* xr4 = (const float4*)(x + (size_t)node * IN_F);
    float acc = 0.f;
    #pragma unroll 8
    for (int k4 = 0; k4 < IN_F / 4; ++k4) {
        float4 xv = xr4[k4];
        acc = fmaf(xv.x, Ws[(4 * k4 + 0) * NF + j], acc);
        acc = fmaf(xv.y, Ws[(4 * k4 + 1) * NF + j], acc);
        acc = fmaf(xv.z, Ws[(4 * k4 + 2) * NF + j], acc);
        acc = fmaf(xv.w, Ws[(4 * k4 + 3) * NF + j], acc);
    }
    rec[(size_t)node * 32 + 8 + j] = __float2half(acc);

    int hd = j >> 1, c = j & 1;
    float vs = acc * att_src[hd * 2 + c];
    float vd = acc * att_dst[hd * 2 + c];
    vs += __shfl_xor(vs, 1);
    vd += __shfl_xor(vd, 1);
    if (c == 0) {
        rec[(size_t)node * 32 + hd] = __float2half(vs * LOG2E);
        adst[node * HEADS + hd] = vd * LOG2E;
    }
}

// ---------------------------------------------------------------------------
// Fused kernel: every 9th block is a bin-role block (SB total), the rest are
// phase1-role (PB total). Bin role: counting-sort a BIN_C-edge chunk by dst
// bin in LDS, reserve per-(block,bin) ranges with ONE global atomic each
// (~306k total), write packed records (d_local<<17 | src) coalesced.
// ---------------------------------------------------------------------------
__global__ __launch_bounds__(512) void fused_p1_bin(
    const int* __restrict__ ei, int* __restrict__ bin_cursor,
    unsigned* __restrict__ bins,
    const float* __restrict__ x, const float* __restrict__ W,
    const float* __restrict__ att_src, const float* __restrict__ att_dst,
    __half* __restrict__ rec, float* __restrict__ adst,
    int E, int SB)
{
    __shared__ union {
        struct {
            unsigned staging[BIN_C];
            unsigned short bin16[BIN_C];
            int hist[NB], offs[NB], cur[NB], gbase[NB];
            int wsum[8], woff[8];
        } b;
        float Ws[IN_F * NF];
    } sm;

    int idx = blockIdx.x;
    bool is_bin = (idx % 9 == 0) && (idx / 9 < SB);
    if (!is_bin) {
        int cb = (idx + 8) / 9; if (cb > SB) cb = SB;
        phase1_body(idx - cb, x, W, att_src, att_dst, rec, adst, sm.Ws);
        return;
    }

    int t = threadIdx.x;
    int base = (idx / 9) * BIN_C;
    int n_valid = E - base;
    if (n_valid > BIN_C) n_valid = BIN_C;
    if (n_valid < 0) n_valid = 0;

    for (int b = t; b < NB; b += 512) sm.b.hist[b] = 0;
    __syncthreads();

    // A: histogram of dst bins
    for (int i = t; i < n_valid; i += 512)
        atomicAdd(&sm.b.hist[ei[E + base + i] >> LOG_RB], 1);
    __syncthreads();

    // B: block-wide exclusive scan of hist (2 bins/thread) + global reserve
    int h2[2], sum = 0;
    #pragma unroll
    for (int k = 0; k < 2; ++k) {
        int b = 2 * t + k;
        h2[k] = (b < NB) ? sm.b.hist[b] : 0;
        sum += h2[k];
    }
    int lane = t & 63, wid = t >> 6;
    int v = sum;
    #pragma unroll
    for (int o = 1; o < 64; o <<= 1) {
        int u = __shfl_up(v, o);
        if (lane >= o) v += u;
    }
    if (lane == 63) sm.b.wsum[wid] = v;
    __syncthreads();
    if (t == 0) { int r = 0; for (int w = 0; w < 8; ++w) { sm.b.woff[w] = r; r += sm.b.wsum[w]; } }
    __syncthreads();
    int run = sm.b.woff[wid] + v - sum;
    #pragma unroll
    for (int k = 0; k < 2; ++k) {
        int b = 2 * t + k;
        if (b < NB) { sm.b.offs[b] = run; sm.b.cur[b] = run; }
        run += h2[k];
    }
    __syncthreads();
    for (int b = t; b < NB; b += 512)
        sm.b.gbase[b] = sm.b.hist[b] ? atomicAdd(&bin_cursor[b], sm.b.hist[b]) : 0;
    __syncthreads();

    // C: counting-sort into LDS staging
    for (int i = t; i < n_valid; i += 512) {
        int s = ei[base + i];
        int d = ei[E + base + i];
        int b = d >> LOG_RB;
        int slot = atomicAdd(&sm.b.cur[b], 1);
        sm.b.staging[slot] = ((unsigned)(d & (RB - 1)) << SBITS) | (unsigned)s;
        sm.b.bin16[slot] = (unsigned short)b;
    }
    __syncthreads();

    // D: coalesced write-out (consecutive slots -> consecutive positions)
    for (int i = t; i < n_valid; i += 512) {
        int b = sm.b.bin16[i];
        int pos = sm.b.gbase[b] + (i - sm.b.offs[b]);
        if (pos < CAPB) bins[(size_t)b * CAPB + pos] = sm.b.staging[i];
    }
}

// ---------------------------------------------------------------------------
// Accum: TWO blocks (512 thr each) per bin segment; block handles 64 nodes
// (half=blk&1), filter-scanning the shared segment. LDS counting sort into
// per-node order (2 LDS atomics/edge), then wave-per-node register gather:
// lane = e_off(0..7) x head(0..7), ONE random 64B line per edge, shuffle
// reduce, fused self-loop + normalize + bias + FC. No fp atomics anywhere.
// ---------------------------------------------------------------------------
__global__ __launch_bounds__(512) void accum2_kernel(
    const unsigned* __restrict__ bins, const int* __restrict__ bin_cursor,
    const __half* __restrict__ rec, const float* __restrict__ adst,
    const float* __restrict__ bias, const float* __restrict__ Wfc,
    const float* __restrict__ bfc, float* __restrict__ out)
{
    __shared__ unsigned staging[HCAP];          // 10 KB
    __shared__ int hist[64], offs[65], cur[64];

    int t = threadIdx.x;
    int sb   = blockIdx.x >> 1;
    int half = blockIdx.x & 1;
    int node0 = sb * RB + half * 64;

    if (t < 64) hist[t] = 0;
    __syncthreads();

    int cnt = bin_cursor[sb];
    if (cnt > CAPB) cnt = CAPB;
    const unsigned* seg = bins + (size_t)sb * CAPB;

    // A: per-node histogram (only this half's nodes)
    for (int i = t; i < cnt; i += 512) {
        int dl = seg[i] >> SBITS;
        if ((dl >> 6) == half) atomicAdd(&hist[dl & 63], 1);
    }
    __syncthreads();

    // B: scan of 64 counters by wave 0
    if (t < 64) {
        int h = hist[t];
        int inc = h;
        #pragma unroll
        for (int o = 1; o < 64; o <<= 1) {
            int u = __shfl_up(inc, o);
            if (t >= o) inc += u;
        }
        offs[t] = inc - h;
        cur[t]  = inc - h;
        if (t == 63) offs[64] = inc;
    }
    __syncthreads();

    // C: sort this half's src ids into per-node order in LDS
    for (int i = t; i < cnt; i += 512) {
        unsigned r = seg[i];
        int dl = r >> SBITS;
        if ((dl >> 6) == half) {
            int slot = atomicAdd(&cur[dl & 63], 1);
            if (slot < HCAP) staging[slot] = r & SMASK;
        }
    }
    __syncthreads();

    // D: wave-per-node gather (8 waves x 8 nodes)
    int wv = t >> 6, lane = t & 63;
    int h_id = lane & 7, e_off = lane >> 3;

    // hoisted per-lane constants
    float b0 = bias[2 * h_id], b1 = bias[2 * h_id + 1];
    float w00 = Wfc[(2 * h_id) * 2 + 0],     w01 = Wfc[(2 * h_id) * 2 + 1];
    float w10 = Wfc[(2 * h_id + 1) * 2 + 0], w11 = Wfc[(2 * h_id + 1) * 2 + 1];
    float c0 = bfc[0], c1 = bfc[1];

    for (int k = 0; k < 8; ++k) {
        int dl = wv + 8 * k;            // wave-uniform
        int n = node0 + dl;
        if (n >= N_NODES) break;
        int st  = offs[dl];
        int end = offs[dl + 1];
        if (st > HCAP) st = HCAP;
        if (end > HCAP) end = HCAP;
        int deg = end - st;

        float adst_h = adst[n * HEADS + h_id];
        float den = 0.f, num0 = 0.f, num1 = 0.f;

        for (int i = e_off; i < deg; i += 8) {
            int s = staging[st + i];                    // LDS broadcast
            const __half* rp = rec + ((size_t)s << 5);  // one 64B line
            float a = __half2float(rp[h_id]);
            __half2 hp = *(const __half2*)(rp + 8 + 2 * h_id);
            float l = a + adst_h;
            l = l > 0.f ? l : NEG_SLOPE * l;
            float p = exp2f(l);
            den += p;
            num0 = fmaf(p, __half2float(hp.x), num0);
            num1 = fmaf(p, __half2float(hp.y), num1);
        }
        #pragma unroll
        for (int m = 8; m < 64; m <<= 1) {
            den  += __shfl_xor(den,  m);
            num0 += __shfl_xor(num0, m);
            num1 += __shfl_xor(num1, m);
        }
        // self-loop folded analytically
        {
            const __half* rp = rec + ((size_t)n << 5);
            float a = __half2float(rp[h_id]);
            __half2 hp = *(const __half2*)(rp + 8 + 2 * h_id);
            float l = a + adst_h;
            l = l > 0.f ? l : NEG_SLOPE * l;
            float p = exp2f(l);
            den += p;
            num0 = fmaf(p, __half2float(hp.x), num0);
            num1 = fmaf(p, __half2float(hp.y), num1);
        }
        // normalize + bias + FC, sum over heads
        float g0 = num0 / den + b0;
        float g1 = num1 / den + b1;
        float o0 = g0 * w00 + g1 * w10;
        float o1 = g0 * w01 + g1 * w11;
        #pragma unroll
        for (int m = 1; m < 8; m <<= 1) {
            o0 += __shfl_xor(o0, m);
            o1 += __shfl_xor(o1, m);
        }
        if (lane == 0) {
            float2 res = { o0 + c0, o1 + c1 };
            *(float2*)(out + (size_t)n * 2) = res;
        }
    }
}

// ---------------------------------------------------------------------------
extern "C" void kernel_launch(void* const* d_in, const int* in_sizes, int n_in,
                              void* d_out, int out_size, void* d_ws, size_t ws_size,
                              hipStream_t stream)
{
    const float* x       = (const float*)d_in[0];
    const int*   ei      = (const int*)d_in[1];   // [2, E]
    const float* W       = (const float*)d_in[3];
    const float* att_src = (const float*)d_in[4];
    const float* att_dst = (const float*)d_in[5];
    const float* bias    = (const float*)d_in[6];
    const float* Wfc     = (const float*)d_in[7];
    const float* bfc     = (const float*)d_in[8];
    float*       out     = (float*)d_out;

    const int E  = in_sizes[1] / 2;
    const int SB = (E + BIN_C - 1) / BIN_C;            // bin-role blocks
    const int PB = (N_NODES * 16 + 511) / 512;         // phase1-role blocks

    // ws layout: rec f16[N*32] (6.4MB) | adst f32[N*8] (3.2MB) |
    //            bin_cursor i32[NB] | (4KB align) | bins u32[NB*CAPB] (~14.6MB)
    __half* rec        = (__half*)d_ws;
    float*  adst       = (float*)((char*)d_ws + (size_t)N_NODES * 32 * 2);
    int*    bin_cursor = (int*)((char*)adst + (size_t)N_NODES * HEADS * 4);
    size_t  bins_off   = (((size_t)((char*)bin_cursor - (char*)d_ws)) + NB * 4 + 4095) & ~(size_t)4095;
    unsigned* bins     = (unsigned*)((char*)d_ws + bins_off);

    hipMemsetAsync(bin_cursor, 0, NB * sizeof(int), stream);

    fused_p1_bin<<<SB + PB, 512, 0, stream>>>(
        ei, bin_cursor, bins, x, W, att_src, att_dst, rec, adst, E, SB);
    accum2_kernel<<<2 * NB, 512, 0, stream>>>(
        bins, bin_cursor, rec, adst, bias, Wfc, bfc, out);
}

// Round 8
// 230.728 us; speedup vs baseline: 3.0302x; 1.0280x over previous
//
#include <hip/hip_runtime.h>
#include <hip/hip_fp16.h>

#define N_NODES 100000
#define IN_F 128
#define NF 16      // HEADS * OUT_C
#define HEADS 8
#define NEG_SLOPE 0.2f
#define LOG2E 1.44269504f

#define RB 128          // nodes per bin (power of 2)
#define LOG_RB 7
#define NB 782          // ceil(100000/128)
#define SBITS 17        // src id bits (100000 < 2^17)
#define SMASK ((1u << SBITS) - 1)
#define BIN_C 4096      // edges per binning block (8/thread @512)
#define CAPB 4672       // per-bin segment capacity: mean 4096 + ~9 sigma
#define HCAP 2560       // half-bin LDS staging capacity (mean 2048 + ~11 sigma)

// Node record rec[n]: 32 halves = 64B, one cache line (f16 proven: absmax 0.0078).
//   [0..7]  = asrc * log2(e), f16
//   [8..23] = h, f16
//   [24..31] pad

// ---------------------------------------------------------------------------
// phase1 role: h = x@W, attention logits. 16 lanes per node, 512-thr blocks.
// ---------------------------------------------------------------------------
__device__ __forceinline__ void phase1_body(
    int pb, const float* __restrict__ x, const float* __restrict__ W,
    const float* __restrict__ att_src, const float* __restrict__ att_dst,
    __half* __restrict__ rec, float* __restrict__ adst, float* Ws)
{
    int t = threadIdx.x;
    for (int i = t; i < IN_F * NF; i += 512) Ws[i] = W[i];
    __syncthreads();

    int tid  = pb * 512 + t;
    int node = tid >> 4;
    int j    = tid & 15;
    if (node >= N_NODES) return;

    const float4* xr4 = (const float4*)(x + (size_t)node * IN_F);
    float acc = 0.f;
    #pragma unroll 8
    for (int k4 = 0; k4 < IN_F / 4; ++k4) {
        float4 xv = xr4[k4];
        acc = fmaf(xv.x, Ws[(4 * k4 + 0) * NF + j], acc);
        acc = fmaf(xv.y, Ws[(4 * k4 + 1) * NF + j], acc);
        acc = fmaf(xv.z, Ws[(4 * k4 + 2) * NF + j], acc);
        acc = fmaf(xv.w, Ws[(4 * k4 + 3) * NF + j], acc);
    }
    __half* rp = rec + ((size_t)node << 5);
    rp[8 + j] = __float2half(acc);

    int hd = j >> 1, c = j & 1;
    float vs = acc * att_src[hd * 2 + c];
    float vd = acc * att_dst[hd * 2 + c];
    vs += __shfl_xor(vs, 1);
    vd += __shfl_xor(vd, 1);
    if (c == 0) {
        rp[hd] = __float2half(vs * LOG2E);
        adst[node * HEADS + hd] = vd * LOG2E;
    }
}

// ---------------------------------------------------------------------------
// Fused kernel: every 5th block is bin-role (SB total), rest phase1 (PB).
// Bin role: load 4096 edges ONCE into registers; LDS counting-sort by dst bin;
// reserve per-(block,bin) ranges with one global atomic each; write packed
// records (d_local<<17 | src) coalesced into per-bin segments.
// LDS 36.3 KB -> 4 blocks/CU.
// ---------------------------------------------------------------------------
__global__ __launch_bounds__(512) void fused_p1_bin(
    const int* __restrict__ ei, int* __restrict__ bin_cursor,
    unsigned* __restrict__ bins,
    const float* __restrict__ x, const float* __restrict__ W,
    const float* __restrict__ att_src, const float* __restrict__ att_dst,
    __half* __restrict__ rec, float* __restrict__ adst,
    int E, int SB)
{
    __shared__ union {
        struct {
            unsigned staging[BIN_C];        // 16 KB
            unsigned short bin16[BIN_C];    // 8 KB
            int hist[NB], offs[NB], cur[NB], gbase[NB]; // 12.5 KB
            int wsum[8], woff[8];
        } b;
        float Ws[IN_F * NF];
    } sm;

    int idx = blockIdx.x;
    bool is_bin = (idx % 5 == 0) && (idx / 5 < SB);
    if (!is_bin) {
        int cb = (idx + 4) / 5; if (cb > SB) cb = SB;
        phase1_body(idx - cb, x, W, att_src, att_dst, rec, adst, sm.Ws);
        return;
    }

    int t = threadIdx.x;
    int base = (idx / 5) * BIN_C;
    int n_valid = E - base;
    if (n_valid > BIN_C) n_valid = BIN_C;
    if (n_valid < 0) n_valid = 0;

    // load this block's edges once, coalesced, into registers
    int es[8], ed[8];
    #pragma unroll
    for (int k = 0; k < 8; ++k) {
        int i = t + 512 * k;
        bool v = i < n_valid;
        es[k] = v ? ei[base + i] : 0;
        ed[k] = v ? ei[E + base + i] : -1;
    }

    for (int b = t; b < NB; b += 512) sm.b.hist[b] = 0;
    __syncthreads();

    // A: histogram of dst bins (from registers)
    #pragma unroll
    for (int k = 0; k < 8; ++k)
        if (ed[k] >= 0) atomicAdd(&sm.b.hist[ed[k] >> LOG_RB], 1);
    __syncthreads();

    // B: block-wide exclusive scan of hist (2 bins/thread) + global reserve
    int h2[2], sum = 0;
    #pragma unroll
    for (int k = 0; k < 2; ++k) {
        int b = 2 * t + k;
        h2[k] = (b < NB) ? sm.b.hist[b] : 0;
        sum += h2[k];
    }
    int lane = t & 63, wid = t >> 6;
    int v = sum;
    #pragma unroll
    for (int o = 1; o < 64; o <<= 1) {
        int u = __shfl_up(v, o);
        if (lane >= o) v += u;
    }
    if (lane == 63) sm.b.wsum[wid] = v;
    __syncthreads();
    if (t == 0) { int r = 0; for (int w = 0; w < 8; ++w) { sm.b.woff[w] = r; r += sm.b.wsum[w]; } }
    __syncthreads();
    int run = sm.b.woff[wid] + v - sum;
    #pragma unroll
    for (int k = 0; k < 2; ++k) {
        int b = 2 * t + k;
        if (b < NB) { sm.b.offs[b] = run; sm.b.cur[b] = run; }
        run += h2[k];
    }
    __syncthreads();
    for (int b = t; b < NB; b += 512)
        sm.b.gbase[b] = sm.b.hist[b] ? atomicAdd(&bin_cursor[b], sm.b.hist[b]) : 0;
    __syncthreads();

    // C: counting-sort into LDS staging (from registers)
    #pragma unroll
    for (int k = 0; k < 8; ++k) {
        if (ed[k] >= 0) {
            int b = ed[k] >> LOG_RB;
            int slot = atomicAdd(&sm.b.cur[b], 1);
            sm.b.staging[slot] = ((unsigned)(ed[k] & (RB - 1)) << SBITS) | (unsigned)es[k];
            sm.b.bin16[slot] = (unsigned short)b;
        }
    }
    __syncthreads();

    // D: coalesced write-out
    for (int i = t; i < n_valid; i += 512) {
        int b = sm.b.bin16[i];
        int pos = sm.b.gbase[b] + (i - sm.b.offs[b]);
        if (pos < CAPB) bins[(size_t)b * CAPB + pos] = sm.b.staging[i];
    }
}

// ---------------------------------------------------------------------------
// Accum: TWO blocks (512 thr) per bin segment; block handles 64 nodes
// (half=blk&1). Segment cached in registers (one global pass). LDS counting
// sort into per-node order, then wave-per-node register gather:
// lane = e_off(0..7) x head(0..7), ONE random 64B line per edge, shuffle
// reduce, fused self-loop + normalize + bias + FC. No fp atomics anywhere.
// ---------------------------------------------------------------------------
__global__ __launch_bounds__(512) void accum3_kernel(
    const unsigned* __restrict__ bins, const int* __restrict__ bin_cursor,
    const __half* __restrict__ rec, const float* __restrict__ adst,
    const float* __restrict__ bias, const float* __restrict__ Wfc,
    const float* __restrict__ bfc, float* __restrict__ out)
{
    __shared__ unsigned staging[HCAP];          // 10 KB
    __shared__ int hist[64], offs[65], cur[64];

    int t = threadIdx.x;
    int sb   = blockIdx.x >> 1;
    int half = blockIdx.x & 1;
    int node0 = sb * RB + half * 64;

    if (t < 64) hist[t] = 0;
    __syncthreads();

    int cnt = bin_cursor[sb];
    if (cnt > CAPB) cnt = CAPB;
    const unsigned* seg = bins + (size_t)sb * CAPB;

    // cache segment in registers (single global pass)
    unsigned rcache[10];
    int nk = 0;
    for (int i = t; i < cnt; i += 512) rcache[nk++] = seg[i];

    // A: per-node histogram (this half only)
    for (int k = 0; k < nk; ++k) {
        int dl = rcache[k] >> SBITS;
        if ((dl >> 6) == half) atomicAdd(&hist[dl & 63], 1);
    }
    __syncthreads();

    // B: scan of 64 counters by wave 0
    if (t < 64) {
        int h = hist[t];
        int inc = h;
        #pragma unroll
        for (int o = 1; o < 64; o <<= 1) {
            int u = __shfl_up(inc, o);
            if (t >= o) inc += u;
        }
        offs[t] = inc - h;
        cur[t]  = inc - h;
        if (t == 63) offs[64] = inc;
    }
    __syncthreads();

    // C: sort this half's src ids into per-node order in LDS
    for (int k = 0; k < nk; ++k) {
        unsigned r = rcache[k];
        int dl = r >> SBITS;
        if ((dl >> 6) == half) {
            int slot = atomicAdd(&cur[dl & 63], 1);
            if (slot < HCAP) staging[slot] = r & SMASK;
        }
    }
    __syncthreads();

    // D: wave-per-node gather (8 waves x 8 nodes)
    int wv = t >> 6, lane = t & 63;
    int h_id = lane & 7, e_off = lane >> 3;

    float b0 = bias[2 * h_id], b1 = bias[2 * h_id + 1];
    float w00 = Wfc[(2 * h_id) * 2 + 0],     w01 = Wfc[(2 * h_id) * 2 + 1];
    float w10 = Wfc[(2 * h_id + 1) * 2 + 0], w11 = Wfc[(2 * h_id + 1) * 2 + 1];
    float c0 = bfc[0], c1 = bfc[1];

    for (int k = 0; k < 8; ++k) {
        int dl = wv + 8 * k;            // wave-uniform
        int n = node0 + dl;
        if (n >= N_NODES) break;
        int st  = offs[dl];
        int end = offs[dl + 1];
        if (st > HCAP) st = HCAP;
        if (end > HCAP) end = HCAP;
        int deg = end - st;

        float adst_h = adst[n * HEADS + h_id];
        float den = 0.f, num0 = 0.f, num1 = 0.f;

        for (int i = e_off; i < deg; i += 8) {
            int s = staging[st + i];                    // LDS broadcast
            const __half* rp = rec + ((size_t)s << 5);  // one 64B line
            float a = __half2float(rp[h_id]);
            __half2 hp = *(const __half2*)(rp + 8 + 2 * h_id);
            float l = a + adst_h;
            l = l > 0.f ? l : NEG_SLOPE * l;
            float p = exp2f(l);
            den += p;
            num0 = fmaf(p, __half2float(hp.x), num0);
            num1 = fmaf(p, __half2float(hp.y), num1);
        }
        #pragma unroll
        for (int m = 8; m < 64; m <<= 1) {
            den  += __shfl_xor(den,  m);
            num0 += __shfl_xor(num0, m);
            num1 += __shfl_xor(num1, m);
        }
        // self-loop folded analytically
        {
            const __half* rp = rec + ((size_t)n << 5);
            float a = __half2float(rp[h_id]);
            __half2 hp = *(const __half2*)(rp + 8 + 2 * h_id);
            float l = a + adst_h;
            l = l > 0.f ? l : NEG_SLOPE * l;
            float p = exp2f(l);
            den += p;
            num0 = fmaf(p, __half2float(hp.x), num0);
            num1 = fmaf(p, __half2float(hp.y), num1);
        }
        // normalize + bias + FC, sum over heads
        float g0 = num0 / den + b0;
        float g1 = num1 / den + b1;
        float o0 = g0 * w00 + g1 * w10;
        float o1 = g0 * w01 + g1 * w11;
        #pragma unroll
        for (int m = 1; m < 8; m <<= 1) {
            o0 += __shfl_xor(o0, m);
            o1 += __shfl_xor(o1, m);
        }
        if (lane == 0) {
            float2 res = { o0 + c0, o1 + c1 };
            *(float2*)(out + (size_t)n * 2) = res;
        }
    }
}

// ---------------------------------------------------------------------------
extern "C" void kernel_launch(void* const* d_in, const int* in_sizes, int n_in,
                              void* d_out, int out_size, void* d_ws, size_t ws_size,
                              hipStream_t stream)
{
    const float* x       = (const float*)d_in[0];
    const int*   ei      = (const int*)d_in[1];   // [2, E]
    const float* W       = (const float*)d_in[3];
    const float* att_src = (const float*)d_in[4];
    const float* att_dst = (const float*)d_in[5];
    const float* bias    = (const float*)d_in[6];
    const float* Wfc     = (const float*)d_in[7];
    const float* bfc     = (const float*)d_in[8];
    float*       out     = (float*)d_out;

    const int E  = in_sizes[1] / 2;
    const int SB = (E + BIN_C - 1) / BIN_C;            // bin-role blocks (782)
    const int PB = (N_NODES * 16 + 511) / 512;         // phase1-role blocks (3125)

    // ws layout: rec f16[N*32] (6.4MB) | adst f32[N*8] (3.2MB) |
    //            bin_cursor i32[NB] | (4KB align) | bins u32[NB*CAPB] (~14.6MB)
    __half* rec        = (__half*)d_ws;
    float*  adst       = (float*)((char*)d_ws + (size_t)N_NODES * 32 * 2);
    int*    bin_cursor = (int*)((char*)adst + (size_t)N_NODES * HEADS * 4);
    size_t  bins_off   = (((size_t)((char*)bin_cursor - (char*)d_ws)) + NB * 4 + 4095) & ~(size_t)4095;
    unsigned* bins     = (unsigned*)((char*)d_ws + bins_off);

    hipMemsetAsync(bin_cursor, 0, NB * sizeof(int), stream);

    fused_p1_bin<<<SB + PB, 512, 0, stream>>>(
        ei, bin_cursor, bins, x, W, att_src, att_dst, rec, adst, E, SB);
    accum3_kernel<<<2 * NB, 512, 0, stream>>>(
        bins, bin_cursor, rec, adst, bias, Wfc, bfc, out);
}

// Round 9
// 218.959 us; speedup vs baseline: 3.1931x; 1.0538x over previous
//
#include <hip/hip_runtime.h>
#include <hip/hip_fp16.h>

#define N_NODES 100000
#define IN_F 128
#define NF 16      // HEADS * OUT_C
#define HEADS 8
#define NEG_SLOPE 0.2f
#define LOG2E 1.44269504f

#define RB 128          // nodes per bin (power of 2)
#define LOG_RB 7
#define NB 782          // ceil(100000/128)
#define SBITS 17        // src id bits (100000 < 2^17)
#define SMASK ((1u << SBITS) - 1)
#define BIN_C 4096      // edges per binning block (8/thread @512)
#define CAPB 4672       // per-bin segment capacity: mean 4096 + ~9 sigma

// Node record rec[n]: 16 halves = 32B. Table = 3.2 MB -> fits each XCD's 4MB L2.
// asrc/adst are NOT stored: computed per edge as 2 FMAs from h with
// lane-constant att coefficients (LOG2E pre-folded).

// ---------------------------------------------------------------------------
// phase1 role: h = x@W only. 16 lanes per node, 512-thr blocks.
// ---------------------------------------------------------------------------
__device__ __forceinline__ void phase1_body(
    int pb, const float* __restrict__ x, const float* __restrict__ W,
    __half* __restrict__ rec, float* Ws)
{
    int t = threadIdx.x;
    for (int i = t; i < IN_F * NF; i += 512) Ws[i] = W[i];
    __syncthreads();

    int tid  = pb * 512 + t;
    int node = tid >> 4;
    int j    = tid & 15;
    if (node >= N_NODES) return;

    const float4* xr4 = (const float4*)(x + (size_t)node * IN_F);
    float acc = 0.f;
    #pragma unroll 8
    for (int k4 = 0; k4 < IN_F / 4; ++k4) {
        float4 xv = xr4[k4];
        acc = fmaf(xv.x, Ws[(4 * k4 + 0) * NF + j], acc);
        acc = fmaf(xv.y, Ws[(4 * k4 + 1) * NF + j], acc);
        acc = fmaf(xv.z, Ws[(4 * k4 + 2) * NF + j], acc);
        acc = fmaf(xv.w, Ws[(4 * k4 + 3) * NF + j], acc);
    }
    rec[(size_t)node * NF + j] = __float2half(acc);
}

// ---------------------------------------------------------------------------
// Fused kernel: every 5th block is bin-role (SB total), rest phase1 (PB).
// Bin role: load 4096 edges ONCE into registers; LDS counting-sort by dst bin;
// reserve per-(block,bin) ranges with one global atomic each; write packed
// records (d_local<<17 | src) coalesced into per-bin segments.
// ---------------------------------------------------------------------------
__global__ __launch_bounds__(512) void fused_p1_bin(
    const int* __restrict__ ei, int* __restrict__ bin_cursor,
    unsigned* __restrict__ bins,
    const float* __restrict__ x, const float* __restrict__ W,
    __half* __restrict__ rec, int E, int SB)
{
    __shared__ union {
        struct {
            unsigned staging[BIN_C];        // 16 KB
            unsigned short bin16[BIN_C];    // 8 KB
            int hist[NB], offs[NB], cur[NB], gbase[NB]; // 12.5 KB
            int wsum[8], woff[8];
        } b;
        float Ws[IN_F * NF];
    } sm;

    int idx = blockIdx.x;
    bool is_bin = (idx % 5 == 0) && (idx / 5 < SB);
    if (!is_bin) {
        int cb = (idx + 4) / 5; if (cb > SB) cb = SB;
        phase1_body(idx - cb, x, W, rec, sm.Ws);
        return;
    }

    int t = threadIdx.x;
    int base = (idx / 5) * BIN_C;
    int n_valid = E - base;
    if (n_valid > BIN_C) n_valid = BIN_C;
    if (n_valid < 0) n_valid = 0;

    // load this block's edges once, coalesced, into registers
    int es[8], ed[8];
    #pragma unroll
    for (int k = 0; k < 8; ++k) {
        int i = t + 512 * k;
        bool v = i < n_valid;
        es[k] = v ? ei[base + i] : 0;
        ed[k] = v ? ei[E + base + i] : -1;
    }

    for (int b = t; b < NB; b += 512) sm.b.hist[b] = 0;
    __syncthreads();

    // A: histogram of dst bins (from registers)
    #pragma unroll
    for (int k = 0; k < 8; ++k)
        if (ed[k] >= 0) atomicAdd(&sm.b.hist[ed[k] >> LOG_RB], 1);
    __syncthreads();

    // B: block-wide exclusive scan of hist (2 bins/thread) + global reserve
    int h2[2], sum = 0;
    #pragma unroll
    for (int k = 0; k < 2; ++k) {
        int b = 2 * t + k;
        h2[k] = (b < NB) ? sm.b.hist[b] : 0;
        sum += h2[k];
    }
    int lane = t & 63, wid = t >> 6;
    int v = sum;
    #pragma unroll
    for (int o = 1; o < 64; o <<= 1) {
        int u = __shfl_up(v, o);
        if (lane >= o) v += u;
    }
    if (lane == 63) sm.b.wsum[wid] = v;
    __syncthreads();
    if (t == 0) { int r = 0; for (int w = 0; w < 8; ++w) { sm.b.woff[w] = r; r += sm.b.wsum[w]; } }
    __syncthreads();
    int run = sm.b.woff[wid] + v - sum;
    #pragma unroll
    for (int k = 0; k < 2; ++k) {
        int b = 2 * t + k;
        if (b < NB) { sm.b.offs[b] = run; sm.b.cur[b] = run; }
        run += h2[k];
    }
    __syncthreads();
    for (int b = t; b < NB; b += 512)
        sm.b.gbase[b] = sm.b.hist[b] ? atomicAdd(&bin_cursor[b], sm.b.hist[b]) : 0;
    __syncthreads();

    // C: counting-sort into LDS staging (from registers)
    #pragma unroll
    for (int k = 0; k < 8; ++k) {
        if (ed[k] >= 0) {
            int b = ed[k] >> LOG_RB;
            int slot = atomicAdd(&sm.b.cur[b], 1);
            sm.b.staging[slot] = ((unsigned)(ed[k] & (RB - 1)) << SBITS) | (unsigned)es[k];
            sm.b.bin16[slot] = (unsigned short)b;
        }
    }
    __syncthreads();

    // D: coalesced write-out
    for (int i = t; i < n_valid; i += 512) {
        int b = sm.b.bin16[i];
        int pos = sm.b.gbase[b] + (i - sm.b.offs[b]);
        if (pos < CAPB) bins[(size_t)b * CAPB + pos] = sm.b.staging[i];
    }
}

// ---------------------------------------------------------------------------
// Accum: ONE block (512 thr, 8 waves) per bin segment (782 blocks -> all
// co-resident, no scheduling tail). Segment cached in registers (one global
// pass), LDS counting-sort into per-node order, then wave-per-node gather:
// lane = e_off(0..7) x head(0..7); ONE 4B load per lane per edge (wave
// covers the 32B rec row); asrc/adst computed as 2 FMAs from h; shuffle
// reduce; fused self-loop + normalize + bias + FC. No fp atomics anywhere.
// ---------------------------------------------------------------------------
__global__ __launch_bounds__(512) void accum4_kernel(
    const unsigned* __restrict__ bins, const int* __restrict__ bin_cursor,
    const __half* __restrict__ rec,
    const float* __restrict__ att_src, const float* __restrict__ att_dst,
    const float* __restrict__ bias, const float* __restrict__ Wfc,
    const float* __restrict__ bfc, float* __restrict__ out)
{
    __shared__ unsigned staging[CAPB];          // 18.7 KB
    __shared__ int hist[RB], offs[RB + 1], cur[RB];

    int t = threadIdx.x;
    int b = blockIdx.x;
    int node0 = b * RB;

    for (int i = t; i < RB; i += 512) hist[i] = 0;
    __syncthreads();

    int cnt = bin_cursor[b];
    if (cnt > CAPB) cnt = CAPB;
    const unsigned* seg = bins + (size_t)b * CAPB;

    // cache segment in registers (single global pass)
    unsigned rcache[10];
    int nk = 0;
    for (int i = t; i < cnt; i += 512) rcache[nk++] = seg[i];

    // A: per-node histogram
    for (int k = 0; k < nk; ++k)
        atomicAdd(&hist[rcache[k] >> SBITS], 1);
    __syncthreads();

    // B: scan of 128 counters by wave 0 (lane l owns bins 2l, 2l+1)
    if (t < 64) {
        int h0 = hist[2 * t], h1 = hist[2 * t + 1];
        int v = h0 + h1;
        int inc = v;
        #pragma unroll
        for (int o = 1; o < 64; o <<= 1) {
            int u = __shfl_up(inc, o);
            if (t >= o) inc += u;
        }
        int ex = inc - v;
        offs[2 * t] = ex;          cur[2 * t] = ex;
        offs[2 * t + 1] = ex + h0; cur[2 * t + 1] = ex + h0;
        if (t == 63) offs[RB] = inc;
    }
    __syncthreads();

    // C: sort src ids into per-node order in LDS
    for (int k = 0; k < nk; ++k) {
        unsigned r = rcache[k];
        int slot = atomicAdd(&cur[r >> SBITS], 1);
        staging[slot] = r & SMASK;
    }
    __syncthreads();

    // D: wave-per-node gather (8 waves x 16 nodes each)
    int wv = t >> 6, lane = t & 63;
    int h_id = lane & 7, e_off = lane >> 3;

    // lane constants: att coefficients (LOG2E folded), FC weights, biases
    float as0 = att_src[2 * h_id] * LOG2E, as1 = att_src[2 * h_id + 1] * LOG2E;
    float ad0 = att_dst[2 * h_id] * LOG2E, ad1 = att_dst[2 * h_id + 1] * LOG2E;
    float b0 = bias[2 * h_id], b1 = bias[2 * h_id + 1];
    float w00 = Wfc[(2 * h_id) * 2 + 0],     w01 = Wfc[(2 * h_id) * 2 + 1];
    float w10 = Wfc[(2 * h_id + 1) * 2 + 0], w11 = Wfc[(2 * h_id + 1) * 2 + 1];
    float c0 = bfc[0], c1 = bfc[1];

    for (int k = 0; k < RB / 8; ++k) {
        int dl = wv + 8 * k;            // wave-uniform
        int n = node0 + dl;
        if (n >= N_NODES) break;
        int st  = offs[dl];
        int deg = offs[dl + 1] - st;

        // this node's own h pair for this head (also used for self-loop)
        __half2 hn = *(const __half2*)(rec + (size_t)n * NF + 2 * h_id);
        float hn0 = __half2float(hn.x), hn1 = __half2float(hn.y);
        float adst_h = ad0 * hn0 + ad1 * hn1;

        float den = 0.f, num0 = 0.f, num1 = 0.f;

        for (int i = e_off; i < deg; i += 8) {
            int s = staging[st + i];                             // LDS broadcast
            __half2 hs = *(const __half2*)(rec + (size_t)s * NF + 2 * h_id);
            float h0 = __half2float(hs.x), h1 = __half2float(hs.y);
            float l = fmaf(as0, h0, fmaf(as1, h1, adst_h));
            l = l > 0.f ? l : NEG_SLOPE * l;
            float p = exp2f(l);
            den += p;
            num0 = fmaf(p, h0, num0);
            num1 = fmaf(p, h1, num1);
        }
        #pragma unroll
        for (int m = 8; m < 64; m <<= 1) {
            den  += __shfl_xor(den,  m);
            num0 += __shfl_xor(num0, m);
            num1 += __shfl_xor(num1, m);
        }
        // self-loop folded analytically
        {
            float l = fmaf(as0, hn0, fmaf(as1, hn1, adst_h));
            l = l > 0.f ? l : NEG_SLOPE * l;
            float p = exp2f(l);
            den += p;
            num0 = fmaf(p, hn0, num0);
            num1 = fmaf(p, hn1, num1);
        }
        // normalize + bias + FC, sum over heads
        float g0 = num0 / den + b0;
        float g1 = num1 / den + b1;
        float o0 = g0 * w00 + g1 * w10;
        float o1 = g0 * w01 + g1 * w11;
        #pragma unroll
        for (int m = 1; m < 8; m <<= 1) {
            o0 += __shfl_xor(o0, m);
            o1 += __shfl_xor(o1, m);
        }
        if (lane == 0) {
            float2 res = { o0 + c0, o1 + c1 };
            *(float2*)(out + (size_t)n * 2) = res;
        }
    }
}

// ---------------------------------------------------------------------------
extern "C" void kernel_launch(void* const* d_in, const int* in_sizes, int n_in,
                              void* d_out, int out_size, void* d_ws, size_t ws_size,
                              hipStream_t stream)
{
    const float* x       = (const float*)d_in[0];
    const int*   ei      = (const int*)d_in[1];   // [2, E]
    const float* W       = (const float*)d_in[3];
    const float* att_src = (const float*)d_in[4];
    const float* att_dst = (const float*)d_in[5];
    const float* bias    = (const float*)d_in[6];
    const float* Wfc     = (const float*)d_in[7];
    const float* bfc     = (const float*)d_in[8];
    float*       out     = (float*)d_out;

    const int E  = in_sizes[1] / 2;
    const int SB = (E + BIN_C - 1) / BIN_C;            // bin-role blocks (782)
    const int PB = (N_NODES * 16 + 511) / 512;         // phase1-role blocks (3125)

    // ws layout: rec f16[N*16] (3.2MB) | bin_cursor i32[NB] | (4KB align) |
    //            bins u32[NB*CAPB] (~14.6MB)
    __half* rec        = (__half*)d_ws;
    int*    bin_cursor = (int*)((char*)d_ws + (size_t)N_NODES * NF * 2);
    size_t  bins_off   = (((size_t)((char*)bin_cursor - (char*)d_ws)) + NB * 4 + 4095) & ~(size_t)4095;
    unsigned* bins     = (unsigned*)((char*)d_ws + bins_off);

    hipMemsetAsync(bin_cursor, 0, NB * sizeof(int), stream);

    fused_p1_bin<<<SB + PB, 512, 0, stream>>>(
        ei, bin_cursor, bins, x, W, rec, E, SB);
    accum4_kernel<<<NB, 512, 0, stream>>>(
        bins, bin_cursor, rec, att_src, att_dst, bias, Wfc, bfc, out);
}

// Round 10
// 217.871 us; speedup vs baseline: 3.2090x; 1.0050x over previous
//
#include <hip/hip_runtime.h>
#include <hip/hip_fp16.h>

#define N_NODES 100000
#define IN_F 128
#define NF 16      // HEADS * OUT_C
#define HEADS 8
#define NEG_SLOPE 0.2f
#define LOG2E 1.44269504f

#define RB 256          // nodes per bin (power of 2)
#define LOG_RB 8
#define NB 391          // ceil(100000/256)
#define SBITS 17        // src id bits (100000 < 2^17)
#define SMASK ((1u << SBITS) - 1)
#define BIN_C 4096      // edges per binning block (8/thread @512)
#define CAPB 9024       // per-bin segment capacity: mean 8184 + ~9 sigma
#define HCAP 4736       // half-bin LDS staging capacity (mean 4092 + ~10 sigma)

// Node record rec[n]: 16 halves = 32B. Table = 3.2 MB -> L2-resident per XCD.
// asrc/adst computed per edge as 2 FMAs from h (att coeffs lane-constant,
// LOG2E pre-folded).

// ---------------------------------------------------------------------------
// phase1 role: h = x@W only. 16 lanes per node, 512-thr blocks.
// ---------------------------------------------------------------------------
__device__ __forceinline__ void phase1_body(
    int pb, const float* __restrict__ x, const float* __restrict__ W,
    __half* __restrict__ rec, float* Ws)
{
    int t = threadIdx.x;
    for (int i = t; i < IN_F * NF; i += 512) Ws[i] = W[i];
    __syncthreads();

    int tid  = pb * 512 + t;
    int node = tid >> 4;
    int j    = tid & 15;
    if (node >= N_NODES) return;

    const float4* xr4 = (const float4*)(x + (size_t)node * IN_F);
    float acc = 0.f;
    #pragma unroll 8
    for (int k4 = 0; k4 < IN_F / 4; ++k4) {
        float4 xv = xr4[k4];
        acc = fmaf(xv.x, Ws[(4 * k4 + 0) * NF + j], acc);
        acc = fmaf(xv.y, Ws[(4 * k4 + 1) * NF + j], acc);
        acc = fmaf(xv.z, Ws[(4 * k4 + 2) * NF + j], acc);
        acc = fmaf(xv.w, Ws[(4 * k4 + 3) * NF + j], acc);
    }
    rec[(size_t)node * NF + j] = __float2half(acc);
}

// ---------------------------------------------------------------------------
// Fused kernel: every 5th block is bin-role (SB total), rest phase1 (PB).
// Bin role: load 4096 edges ONCE into registers; LDS counting-sort by dst bin
// (391 bins of 256 nodes -> ~half the reserve atomics and 2x-longer write
// runs vs 782 bins); reserve per-(block,bin) ranges with one global atomic
// each; write packed records (d_local<<17 | src) coalesced.
// ---------------------------------------------------------------------------
__global__ __launch_bounds__(512) void fused_p1_bin(
    const int* __restrict__ ei, int* __restrict__ bin_cursor,
    unsigned* __restrict__ bins,
    const float* __restrict__ x, const float* __restrict__ W,
    __half* __restrict__ rec, int E, int SB)
{
    __shared__ union {
        struct {
            unsigned staging[BIN_C];        // 16 KB
            unsigned short bin16[BIN_C];    // 8 KB
            int hist[NB], offs[NB], cur[NB], gbase[NB]; // 6.3 KB
            int wsum[8], woff[8];
        } b;
        float Ws[IN_F * NF];
    } sm;

    int idx = blockIdx.x;
    bool is_bin = (idx % 5 == 0) && (idx / 5 < SB);
    if (!is_bin) {
        int cb = (idx + 4) / 5; if (cb > SB) cb = SB;
        phase1_body(idx - cb, x, W, rec, sm.Ws);
        return;
    }

    int t = threadIdx.x;
    int base = (idx / 5) * BIN_C;
    int n_valid = E - base;
    if (n_valid > BIN_C) n_valid = BIN_C;
    if (n_valid < 0) n_valid = 0;

    // load this block's edges once, coalesced, into registers
    int es[8], ed[8];
    #pragma unroll
    for (int k = 0; k < 8; ++k) {
        int i = t + 512 * k;
        bool v = i < n_valid;
        es[k] = v ? ei[base + i] : 0;
        ed[k] = v ? ei[E + base + i] : -1;
    }

    if (t < NB) sm.b.hist[t] = 0;
    __syncthreads();

    // A: histogram of dst bins (from registers)
    #pragma unroll
    for (int k = 0; k < 8; ++k)
        if (ed[k] >= 0) atomicAdd(&sm.b.hist[ed[k] >> LOG_RB], 1);
    __syncthreads();

    // B: block-wide exclusive scan of hist (1 bin/thread) + global reserve
    int sum = (t < NB) ? sm.b.hist[t] : 0;
    int lane = t & 63, wid = t >> 6;
    int v = sum;
    #pragma unroll
    for (int o = 1; o < 64; o <<= 1) {
        int u = __shfl_up(v, o);
        if (lane >= o) v += u;
    }
    if (lane == 63) sm.b.wsum[wid] = v;
    __syncthreads();
    if (t == 0) { int r = 0; for (int w = 0; w < 8; ++w) { sm.b.woff[w] = r; r += sm.b.wsum[w]; } }
    __syncthreads();
    int run = sm.b.woff[wid] + v - sum;
    if (t < NB) { sm.b.offs[t] = run; sm.b.cur[t] = run; }
    __syncthreads();
    if (t < NB)
        sm.b.gbase[t] = sm.b.hist[t] ? atomicAdd(&bin_cursor[t], sm.b.hist[t]) : 0;
    __syncthreads();

    // C: counting-sort into LDS staging (from registers)
    #pragma unroll
    for (int k = 0; k < 8; ++k) {
        if (ed[k] >= 0) {
            int b = ed[k] >> LOG_RB;
            int slot = atomicAdd(&sm.b.cur[b], 1);
            sm.b.staging[slot] = ((unsigned)(ed[k] & (RB - 1)) << SBITS) | (unsigned)es[k];
            sm.b.bin16[slot] = (unsigned short)b;
        }
    }
    __syncthreads();

    // D: coalesced write-out (runs of ~10.5 consecutive slots per bin)
    for (int i = t; i < n_valid; i += 512) {
        int b = sm.b.bin16[i];
        int pos = sm.b.gbase[b] + (i - sm.b.offs[b]);
        if (pos < CAPB) bins[(size_t)b * CAPB + pos] = sm.b.staging[i];
    }
}

// ---------------------------------------------------------------------------
// Accum: TWO blocks (512 thr, 8 waves) per 256-node bin; block handles 128
// nodes (half=blk&1). Segment register-cached in ONE global pass; LDS
// counting-sort of this half's edges into per-node order; then wave-per-node
// gather: lane = e_off(0..7) x head(0..7); ONE 4B load per lane per edge
// (8 lanes cover the 32B rec row -> 1 transaction/edge); asrc/adst computed
// as FMAs from h; shuffle reduce; fused self-loop + normalize + bias + FC.
// No fp atomics anywhere.
// ---------------------------------------------------------------------------
__global__ __launch_bounds__(512) void accum5_kernel(
    const unsigned* __restrict__ bins, const int* __restrict__ bin_cursor,
    const __half* __restrict__ rec,
    const float* __restrict__ att_src, const float* __restrict__ att_dst,
    const float* __restrict__ bias, const float* __restrict__ Wfc,
    const float* __restrict__ bfc, float* __restrict__ out)
{
    __shared__ unsigned staging[HCAP];          // 18.5 KB
    __shared__ int hist[128], offs[129], cur[128];

    int t = threadIdx.x;
    int sb   = blockIdx.x >> 1;
    int half = blockIdx.x & 1;
    int node0 = sb * RB + half * 128;

    if (t < 128) hist[t] = 0;
    __syncthreads();

    int cnt = bin_cursor[sb];
    if (cnt > CAPB) cnt = CAPB;
    const unsigned* seg = bins + (size_t)sb * CAPB;

    // cache segment in registers (single global pass)
    unsigned rcache[18];
    int nk = 0;
    for (int i = t; i < cnt; i += 512) rcache[nk++] = seg[i];

    // A: per-node histogram (this half's 128 nodes only)
    for (int k = 0; k < nk; ++k) {
        int dl = rcache[k] >> SBITS;
        if ((dl >> 7) == half) atomicAdd(&hist[dl & 127], 1);
    }
    __syncthreads();

    // B: scan of 128 counters by wave 0 (lane l owns nodes 2l, 2l+1)
    if (t < 64) {
        int h0 = hist[2 * t], h1 = hist[2 * t + 1];
        int v = h0 + h1;
        int inc = v;
        #pragma unroll
        for (int o = 1; o < 64; o <<= 1) {
            int u = __shfl_up(inc, o);
            if (t >= o) inc += u;
        }
        int ex = inc - v;
        offs[2 * t] = ex;          cur[2 * t] = ex;
        offs[2 * t + 1] = ex + h0; cur[2 * t + 1] = ex + h0;
        if (t == 63) offs[128] = inc;
    }
    __syncthreads();

    // C: sort this half's src ids into per-node order in LDS
    for (int k = 0; k < nk; ++k) {
        unsigned r = rcache[k];
        int dl = r >> SBITS;
        if ((dl >> 7) == half) {
            int slot = atomicAdd(&cur[dl & 127], 1);
            if (slot < HCAP) staging[slot] = r & SMASK;
        }
    }
    __syncthreads();

    // D: wave-per-node gather (8 waves x 16 nodes each)
    int wv = t >> 6, lane = t & 63;
    int h_id = lane & 7, e_off = lane >> 3;

    // lane constants: att coefficients (LOG2E folded), FC weights, biases
    float as0 = att_src[2 * h_id] * LOG2E, as1 = att_src[2 * h_id + 1] * LOG2E;
    float ad0 = att_dst[2 * h_id] * LOG2E, ad1 = att_dst[2 * h_id + 1] * LOG2E;
    float b0 = bias[2 * h_id], b1 = bias[2 * h_id + 1];
    float w00 = Wfc[(2 * h_id) * 2 + 0],     w01 = Wfc[(2 * h_id) * 2 + 1];
    float w10 = Wfc[(2 * h_id + 1) * 2 + 0], w11 = Wfc[(2 * h_id + 1) * 2 + 1];
    float c0 = bfc[0], c1 = bfc[1];

    for (int k = 0; k < 16; ++k) {
        int ln = wv + 8 * k;            // wave-uniform local node
        int n = node0 + ln;
        if (n >= N_NODES) break;
        int st  = offs[ln];
        int end = offs[ln + 1];
        if (st > HCAP) st = HCAP;
        if (end > HCAP) end = HCAP;
        int deg = end - st;

        // this node's own h pair for this head (also used for self-loop)
        __half2 hn = *(const __half2*)(rec + (size_t)n * NF + 2 * h_id);
        float hn0 = __half2float(hn.x), hn1 = __half2float(hn.y);
        float adst_h = ad0 * hn0 + ad1 * hn1;

        float den = 0.f, num0 = 0.f, num1 = 0.f;

        for (int i = e_off; i < deg; i += 8) {
            int s = staging[st + i];                             // LDS broadcast
            __half2 hs = *(const __half2*)(rec + (size_t)s * NF + 2 * h_id);
            float h0 = __half2float(hs.x), h1 = __half2float(hs.y);
            float l = fmaf(as0, h0, fmaf(as1, h1, adst_h));
            l = l > 0.f ? l : NEG_SLOPE * l;
            float p = exp2f(l);
            den += p;
            num0 = fmaf(p, h0, num0);
            num1 = fmaf(p, h1, num1);
        }
        #pragma unroll
        for (int m = 8; m < 64; m <<= 1) {
            den  += __shfl_xor(den,  m);
            num0 += __shfl_xor(num0, m);
            num1 += __shfl_xor(num1, m);
        }
        // self-loop folded analytically
        {
            float l = fmaf(as0, hn0, fmaf(as1, hn1, adst_h));
            l = l > 0.f ? l : NEG_SLOPE * l;
            float p = exp2f(l);
            den += p;
            num0 = fmaf(p, hn0, num0);
            num1 = fmaf(p, hn1, num1);
        }
        // normalize + bias + FC, sum over heads
        float g0 = num0 / den + b0;
        float g1 = num1 / den + b1;
        float o0 = g0 * w00 + g1 * w10;
        float o1 = g0 * w01 + g1 * w11;
        #pragma unroll
        for (int m = 1; m < 8; m <<= 1) {
            o0 += __shfl_xor(o0, m);
            o1 += __shfl_xor(o1, m);
        }
        if (lane == 0) {
            float2 res = { o0 + c0, o1 + c1 };
            *(float2*)(out + (size_t)n * 2) = res;
        }
    }
}

// ---------------------------------------------------------------------------
extern "C" void kernel_launch(void* const* d_in, const int* in_sizes, int n_in,
                              void* d_out, int out_size, void* d_ws, size_t ws_size,
                              hipStream_t stream)
{
    const float* x       = (const float*)d_in[0];
    const int*   ei      = (const int*)d_in[1];   // [2, E]
    const float* W       = (const float*)d_in[3];
    const float* att_src = (const float*)d_in[4];
    const float* att_dst = (const float*)d_in[5];
    const float* bias    = (const float*)d_in[6];
    const float* Wfc     = (const float*)d_in[7];
    const float* bfc     = (const float*)d_in[8];
    float*       out     = (float*)d_out;

    const int E  = in_sizes[1] / 2;
    const int SB = (E + BIN_C - 1) / BIN_C;            // bin-role blocks (782)
    const int PB = (N_NODES * 16 + 511) / 512;         // phase1-role blocks (3125)

    // ws layout: rec f16[N*16] (3.2MB) | bin_cursor i32[NB] | (4KB align) |
    //            bins u32[NB*CAPB] (~14.1MB)
    __half* rec        = (__half*)d_ws;
    int*    bin_cursor = (int*)((char*)d_ws + (size_t)N_NODES * NF * 2);
    size_t  bins_off   = (((size_t)((char*)bin_cursor - (char*)d_ws)) + NB * 4 + 4095) & ~(size_t)4095;
    unsigned* bins     = (unsigned*)((char*)d_ws + bins_off);

    hipMemsetAsync(bin_cursor, 0, NB * sizeof(int), stream);

    fused_p1_bin<<<SB + PB, 512, 0, stream>>>(
        ei, bin_cursor, bins, x, W, rec, E, SB);
    accum5_kernel<<<2 * NB, 512, 0, stream>>>(
        bins, bin_cursor, rec, att_src, att_dst, bias, Wfc, bfc, out);
}

// Round 11
// 210.727 us; speedup vs baseline: 3.3178x; 1.0339x over previous
//
#include <hip/hip_runtime.h>
#include <hip/hip_fp16.h>

#define N_NODES 100000
#define IN_F 128
#define NF 16      // HEADS * OUT_C
#define HEADS 8
#define NEG_SLOPE 0.2f
#define LOG2E 1.44269504f

#define RB 256          // nodes per bin (power of 2)
#define LOG_RB 8
#define NB 391          // ceil(100000/256)
#define SBITS 17        // src id bits (100000 < 2^17)
#define SMASK ((1u << SBITS) - 1)
#define BIN_C 4096      // edges per binning block (8/thread @512)
#define CAPB 9024       // per-bin segment capacity: mean 8184 + ~9 sigma

// Node record rec[n]: 16 halves = 32B. Table = 3.2 MB -> L2-resident per XCD
// (verified: accum FETCH ~= 3.2MB x 8 XCDs). asrc/adst computed per edge as
// 2 FMAs from h (att coeffs lane-constant, LOG2E pre-folded).

// ---------------------------------------------------------------------------
// phase1 role: h = x@W only. 16 lanes per node, 512-thr blocks.
// Two accumulators break the 128-deep dependent FMA chain (4cyc latency).
// ---------------------------------------------------------------------------
__device__ __forceinline__ void phase1_body(
    int pb, const float* __restrict__ x, const float* __restrict__ W,
    __half* __restrict__ rec, float* Ws)
{
    int t = threadIdx.x;
    for (int i = t; i < IN_F * NF; i += 512) Ws[i] = W[i];
    __syncthreads();

    int tid  = pb * 512 + t;
    int node = tid >> 4;
    int j    = tid & 15;
    if (node >= N_NODES) return;

    const float4* xr4 = (const float4*)(x + (size_t)node * IN_F);
    float acc0 = 0.f, acc1 = 0.f;
    #pragma unroll 8
    for (int k4 = 0; k4 < IN_F / 4; k4 += 2) {
        float4 xa = xr4[k4];
        float4 xb = xr4[k4 + 1];
        acc0 = fmaf(xa.x, Ws[(4 * k4 + 0) * NF + j], acc0);
        acc0 = fmaf(xa.y, Ws[(4 * k4 + 1) * NF + j], acc0);
        acc0 = fmaf(xa.z, Ws[(4 * k4 + 2) * NF + j], acc0);
        acc0 = fmaf(xa.w, Ws[(4 * k4 + 3) * NF + j], acc0);
        acc1 = fmaf(xb.x, Ws[(4 * k4 + 4) * NF + j], acc1);
        acc1 = fmaf(xb.y, Ws[(4 * k4 + 5) * NF + j], acc1);
        acc1 = fmaf(xb.z, Ws[(4 * k4 + 6) * NF + j], acc1);
        acc1 = fmaf(xb.w, Ws[(4 * k4 + 7) * NF + j], acc1);
    }
    rec[(size_t)node * NF + j] = __float2half(acc0 + acc1);
}

// ---------------------------------------------------------------------------
// Fused kernel: every 5th block is bin-role (SB total), rest phase1 (PB).
// Bin role: load 4096 edges ONCE into registers; LDS counting-sort by dst bin
// (391 bins of 256 nodes); reserve per-(block,bin) ranges with one global
// atomic each; write packed records (d_local<<17 | src) coalesced.
// ---------------------------------------------------------------------------
__global__ __launch_bounds__(512) void fused_p1_bin(
    const int* __restrict__ ei, int* __restrict__ bin_cursor,
    unsigned* __restrict__ bins,
    const float* __restrict__ x, const float* __restrict__ W,
    __half* __restrict__ rec, int E, int SB)
{
    __shared__ union {
        struct {
            unsigned staging[BIN_C];        // 16 KB
            unsigned short bin16[BIN_C];    // 8 KB
            int hist[NB], offs[NB], cur[NB], gbase[NB]; // 6.3 KB
            int wsum[8], woff[8];
        } b;
        float Ws[IN_F * NF];
    } sm;

    int idx = blockIdx.x;
    bool is_bin = (idx % 5 == 0) && (idx / 5 < SB);
    if (!is_bin) {
        int cb = (idx + 4) / 5; if (cb > SB) cb = SB;
        phase1_body(idx - cb, x, W, rec, sm.Ws);
        return;
    }

    int t = threadIdx.x;
    int base = (idx / 5) * BIN_C;
    int n_valid = E - base;
    if (n_valid > BIN_C) n_valid = BIN_C;
    if (n_valid < 0) n_valid = 0;

    // load this block's edges once, coalesced, into registers
    int es[8], ed[8];
    #pragma unroll
    for (int k = 0; k < 8; ++k) {
        int i = t + 512 * k;
        bool v = i < n_valid;
        es[k] = v ? ei[base + i] : 0;
        ed[k] = v ? ei[E + base + i] : -1;
    }

    if (t < NB) sm.b.hist[t] = 0;
    __syncthreads();

    // A: histogram of dst bins (from registers)
    #pragma unroll
    for (int k = 0; k < 8; ++k)
        if (ed[k] >= 0) atomicAdd(&sm.b.hist[ed[k] >> LOG_RB], 1);
    __syncthreads();

    // B: block-wide exclusive scan of hist (1 bin/thread) + global reserve
    int sum = (t < NB) ? sm.b.hist[t] : 0;
    int lane = t & 63, wid = t >> 6;
    int v = sum;
    #pragma unroll
    for (int o = 1; o < 64; o <<= 1) {
        int u = __shfl_up(v, o);
        if (lane >= o) v += u;
    }
    if (lane == 63) sm.b.wsum[wid] = v;
    __syncthreads();
    if (t == 0) { int r = 0; for (int w = 0; w < 8; ++w) { sm.b.woff[w] = r; r += sm.b.wsum[w]; } }
    __syncthreads();
    int run = sm.b.woff[wid] + v - sum;
    if (t < NB) { sm.b.offs[t] = run; sm.b.cur[t] = run; }
    __syncthreads();
    if (t < NB)
        sm.b.gbase[t] = sm.b.hist[t] ? atomicAdd(&bin_cursor[t], sm.b.hist[t]) : 0;
    __syncthreads();

    // C: counting-sort into LDS staging (from registers)
    #pragma unroll
    for (int k = 0; k < 8; ++k) {
        if (ed[k] >= 0) {
            int b = ed[k] >> LOG_RB;
            int slot = atomicAdd(&sm.b.cur[b], 1);
            sm.b.staging[slot] = ((unsigned)(ed[k] & (RB - 1)) << SBITS) | (unsigned)es[k];
            sm.b.bin16[slot] = (unsigned short)b;
        }
    }
    __syncthreads();

    // D: coalesced write-out (runs of ~10.5 consecutive slots per bin)
    for (int i = t; i < n_valid; i += 512) {
        int b = sm.b.bin16[i];
        int pos = sm.b.gbase[b] + (i - sm.b.offs[b]);
        if (pos < CAPB) bins[(size_t)b * CAPB + pos] = sm.b.staging[i];
    }
}

// ---------------------------------------------------------------------------
// Accum: ONE 1024-thread block (16 waves) per 256-node bin (391 blocks, all
// co-resident in a single scheduling round). Segment register-cached in ONE
// global pass (no half-filter, no redundant read); LDS counting-sort into
// per-node order; then wave-per-node gather: lane = e_off(0..7) x head(0..7);
// ONE 4B load per lane per edge (8 lanes cover the 32B rec row -> 1
// transaction/edge, the measured ~58 G/s random-transaction wall); asrc/adst
// computed as FMAs from h; shuffle reduce; fused self-loop + normalize +
// bias + FC. No fp atomics anywhere.
// ---------------------------------------------------------------------------
__global__ __launch_bounds__(1024) void accum6_kernel(
    const unsigned* __restrict__ bins, const int* __restrict__ bin_cursor,
    const __half* __restrict__ rec,
    const float* __restrict__ att_src, const float* __restrict__ att_dst,
    const float* __restrict__ bias, const float* __restrict__ Wfc,
    const float* __restrict__ bfc, float* __restrict__ out)
{
    __shared__ unsigned staging[CAPB];          // 35.3 KB
    __shared__ int hist[RB], offs[RB + 1], cur[RB];

    int t = threadIdx.x;
    int b = blockIdx.x;
    int node0 = b * RB;

    if (t < RB) hist[t] = 0;
    __syncthreads();

    int cnt = bin_cursor[b];
    if (cnt > CAPB) cnt = CAPB;
    const unsigned* seg = bins + (size_t)b * CAPB;

    // cache segment in registers (single global pass)
    unsigned rcache[9];
    int nk = 0;
    for (int i = t; i < cnt; i += 1024) rcache[nk++] = seg[i];

    // A: per-node histogram
    for (int k = 0; k < nk; ++k)
        atomicAdd(&hist[rcache[k] >> SBITS], 1);
    __syncthreads();

    // B: scan of 256 counters by wave 0 (lane l owns nodes 4l..4l+3)
    if (t < 64) {
        int h0 = hist[4 * t], h1 = hist[4 * t + 1];
        int h2 = hist[4 * t + 2], h3 = hist[4 * t + 3];
        int v = h0 + h1 + h2 + h3;
        int inc = v;
        #pragma unroll
        for (int o = 1; o < 64; o <<= 1) {
            int u = __shfl_up(inc, o);
            if (t >= o) inc += u;
        }
        int ex = inc - v;
        offs[4 * t] = ex;     cur[4 * t] = ex;     ex += h0;
        offs[4 * t + 1] = ex; cur[4 * t + 1] = ex; ex += h1;
        offs[4 * t + 2] = ex; cur[4 * t + 2] = ex; ex += h2;
        offs[4 * t + 3] = ex; cur[4 * t + 3] = ex;
        if (t == 63) offs[RB] = inc;
    }
    __syncthreads();

    // C: sort src ids into per-node order in LDS
    for (int k = 0; k < nk; ++k) {
        unsigned r = rcache[k];
        int slot = atomicAdd(&cur[r >> SBITS], 1);
        staging[slot] = r & SMASK;
    }
    __syncthreads();

    // D: wave-per-node gather (16 waves x 16 nodes each)
    int wv = t >> 6, lane = t & 63;
    int h_id = lane & 7, e_off = lane >> 3;

    // lane constants: att coefficients (LOG2E folded), FC weights, biases
    float as0 = att_src[2 * h_id] * LOG2E, as1 = att_src[2 * h_id + 1] * LOG2E;
    float ad0 = att_dst[2 * h_id] * LOG2E, ad1 = att_dst[2 * h_id + 1] * LOG2E;
    float b0 = bias[2 * h_id], b1 = bias[2 * h_id + 1];
    float w00 = Wfc[(2 * h_id) * 2 + 0],     w01 = Wfc[(2 * h_id) * 2 + 1];
    float w10 = Wfc[(2 * h_id + 1) * 2 + 0], w11 = Wfc[(2 * h_id + 1) * 2 + 1];
    float c0 = bfc[0], c1 = bfc[1];

    for (int k = 0; k < RB / 16; ++k) {
        int ln = wv + 16 * k;           // wave-uniform local node
        int n = node0 + ln;
        if (n >= N_NODES) break;
        int st  = offs[ln];
        int deg = offs[ln + 1] - st;

        // this node's own h pair for this head (also used for self-loop)
        __half2 hn = *(const __half2*)(rec + (size_t)n * NF + 2 * h_id);
        float hn0 = __half2float(hn.x), hn1 = __half2float(hn.y);
        float adst_h = ad0 * hn0 + ad1 * hn1;

        float den = 0.f, num0 = 0.f, num1 = 0.f;

        for (int i = e_off; i < deg; i += 8) {
            int s = staging[st + i];                             // LDS broadcast
            __half2 hs = *(const __half2*)(rec + (size_t)s * NF + 2 * h_id);
            float h0 = __half2float(hs.x), h1 = __half2float(hs.y);
            float l = fmaf(as0, h0, fmaf(as1, h1, adst_h));
            l = l > 0.f ? l : NEG_SLOPE * l;
            float p = exp2f(l);
            den += p;
            num0 = fmaf(p, h0, num0);
            num1 = fmaf(p, h1, num1);
        }
        #pragma unroll
        for (int m = 8; m < 64; m <<= 1) {
            den  += __shfl_xor(den,  m);
            num0 += __shfl_xor(num0, m);
            num1 += __shfl_xor(num1, m);
        }
        // self-loop folded analytically
        {
            float l = fmaf(as0, hn0, fmaf(as1, hn1, adst_h));
            l = l > 0.f ? l : NEG_SLOPE * l;
            float p = exp2f(l);
            den += p;
            num0 = fmaf(p, hn0, num0);
            num1 = fmaf(p, hn1, num1);
        }
        // normalize + bias + FC, sum over heads
        float g0 = num0 / den + b0;
        float g1 = num1 / den + b1;
        float o0 = g0 * w00 + g1 * w10;
        float o1 = g0 * w01 + g1 * w11;
        #pragma unroll
        for (int m = 1; m < 8; m <<= 1) {
            o0 += __shfl_xor(o0, m);
            o1 += __shfl_xor(o1, m);
        }
        if (lane == 0) {
            float2 res = { o0 + c0, o1 + c1 };
            *(float2*)(out + (size_t)n * 2) = res;
        }
    }
}

// ---------------------------------------------------------------------------
extern "C" void kernel_launch(void* const* d_in, const int* in_sizes, int n_in,
                              void* d_out, int out_size, void* d_ws, size_t ws_size,
                              hipStream_t stream)
{
    const float* x       = (const float*)d_in[0];
    const int*   ei      = (const int*)d_in[1];   // [2, E]
    const float* W       = (const float*)d_in[3];
    const float* att_src = (const float*)d_in[4];
    const float* att_dst = (const float*)d_in[5];
    const float* bias    = (const float*)d_in[6];
    const float* Wfc     = (const float*)d_in[7];
    const float* bfc     = (const float*)d_in[8];
    float*       out     = (float*)d_out;

    const int E  = in_sizes[1] / 2;
    const int SB = (E + BIN_C - 1) / BIN_C;            // bin-role blocks (782)
    const int PB = (N_NODES * 16 + 511) / 512;         // phase1-role blocks (3125)

    // ws layout: rec f16[N*16] (3.2MB) | bin_cursor i32[NB] | (4KB align) |
    //            bins u32[NB*CAPB] (~14.1MB)
    __half* rec        = (__half*)d_ws;
    int*    bin_cursor = (int*)((char*)d_ws + (size_t)N_NODES * NF * 2);
    size_t  bins_off   = (((size_t)((char*)bin_cursor - (char*)d_ws)) + NB * 4 + 4095) & ~(size_t)4095;
    unsigned* bins     = (unsigned*)((char*)d_ws + bins_off);

    hipMemsetAsync(bin_cursor, 0, NB * sizeof(int), stream);

    fused_p1_bin<<<SB + PB, 512, 0, stream>>>(
        ei, bin_cursor, bins, x, W, rec, E, SB);
    accum6_kernel<<<NB, 1024, 0, stream>>>(
        bins, bin_cursor, rec, att_src, att_dst, bias, Wfc, bfc, out);
}

// Round 12
// 203.441 us; speedup vs baseline: 3.4366x; 1.0358x over previous
//
#include <hip/hip_runtime.h>
#include <hip/hip_fp16.h>

#define N_NODES 100000
#define IN_F 128
#define NF 16      // HEADS * OUT_C
#define HEADS 8
#define NEG_SLOPE 0.2f
#define LOG2E 1.44269504f

#define RB 256          // nodes per bin (power of 2)
#define LOG_RB 8
#define NB 391          // ceil(100000/256)
#define SBITS 17        // src id bits (100000 < 2^17)
#define SMASK ((1u << SBITS) - 1)
#define BIN_C 4096      // edges per binning block (8/thread @512)
#define CAPB 9024       // per-bin segment capacity: mean 8184 + ~9 sigma

// Node record rec[n]: 16 halves = 32B. Table = 3.2 MB -> L2-resident per XCD
// (verified: accum FETCH ~= 3.2MB x 8 XCDs). asrc/adst computed per edge as
// 2 FMAs from h (att coeffs lane-constant, LOG2E pre-folded).

// ---------------------------------------------------------------------------
// phase1 role: h = x@W. 8 lanes per node, each lane computes an output PAIR
// (float2 LDS reads halve ds_read count vs 16-lane/b32; 4 accumulators give
// 2-way FMA-chain ILP). 512-thr blocks -> 64 nodes/block.
// ---------------------------------------------------------------------------
__device__ __forceinline__ void phase1_body(
    int pb, const float* __restrict__ x, const float* __restrict__ W,
    __half* __restrict__ rec, float* Ws)
{
    int t = threadIdx.x;
    for (int i = t; i < IN_F * NF; i += 512) Ws[i] = W[i];
    __syncthreads();

    int tid  = pb * 512 + t;
    int node = tid >> 3;
    int j    = tid & 7;         // output-pair index (cols 2j, 2j+1)
    if (node >= N_NODES) return;

    const float4* xr4 = (const float4*)(x + (size_t)node * IN_F);
    const float2* Wp  = (const float2*)Ws;   // pair (k, j) at index k*8 + j

    float a0 = 0.f, b0 = 0.f, a1 = 0.f, b1 = 0.f;
    #pragma unroll 8
    for (int k4 = 0; k4 < IN_F / 4; ++k4) {
        float4 xv = xr4[k4];
        float2 w0 = Wp[(4 * k4 + 0) * 8 + j];
        float2 w1 = Wp[(4 * k4 + 1) * 8 + j];
        float2 w2 = Wp[(4 * k4 + 2) * 8 + j];
        float2 w3 = Wp[(4 * k4 + 3) * 8 + j];
        a0 = fmaf(xv.x, w0.x, a0); b0 = fmaf(xv.x, w0.y, b0);
        a1 = fmaf(xv.y, w1.x, a1); b1 = fmaf(xv.y, w1.y, b1);
        a0 = fmaf(xv.z, w2.x, a0); b0 = fmaf(xv.z, w2.y, b0);
        a1 = fmaf(xv.w, w3.x, a1); b1 = fmaf(xv.w, w3.y, b1);
    }
    __half2 hv = __floats2half2_rn(a0 + a1, b0 + b1);
    *(__half2*)(rec + (size_t)node * NF + 2 * j) = hv;   // 8 lanes cover 32B
}

// ---------------------------------------------------------------------------
// Fused kernel: every 3rd block is bin-role (SB total), rest phase1 (PB).
// Bin role: load 4096 edges ONCE into registers; LDS counting-sort by dst bin
// (391 bins of 256 nodes); reserve per-(block,bin) ranges with one global
// atomic each; write packed records (d_local<<17 | src) coalesced.
// ---------------------------------------------------------------------------
__global__ __launch_bounds__(512) void fused_p1_bin(
    const int* __restrict__ ei, int* __restrict__ bin_cursor,
    unsigned* __restrict__ bins,
    const float* __restrict__ x, const float* __restrict__ W,
    __half* __restrict__ rec, int E, int SB)
{
    __shared__ union {
        struct {
            unsigned staging[BIN_C];        // 16 KB
            unsigned short bin16[BIN_C];    // 8 KB
            int hist[NB], offs[NB], cur[NB], gbase[NB]; // 6.3 KB
            int wsum[8], woff[8];
        } b;
        float Ws[IN_F * NF];
    } sm;

    int idx = blockIdx.x;
    bool is_bin = (idx % 3 == 0) && (idx / 3 < SB);
    if (!is_bin) {
        int cb = (idx + 2) / 3; if (cb > SB) cb = SB;
        phase1_body(idx - cb, x, W, rec, sm.Ws);
        return;
    }

    int t = threadIdx.x;
    int base = (idx / 3) * BIN_C;
    int n_valid = E - base;
    if (n_valid > BIN_C) n_valid = BIN_C;
    if (n_valid < 0) n_valid = 0;

    // load this block's edges once, coalesced, into registers
    int es[8], ed[8];
    #pragma unroll
    for (int k = 0; k < 8; ++k) {
        int i = t + 512 * k;
        bool v = i < n_valid;
        es[k] = v ? ei[base + i] : 0;
        ed[k] = v ? ei[E + base + i] : -1;
    }

    if (t < NB) sm.b.hist[t] = 0;
    __syncthreads();

    // A: histogram of dst bins (from registers)
    #pragma unroll
    for (int k = 0; k < 8; ++k)
        if (ed[k] >= 0) atomicAdd(&sm.b.hist[ed[k] >> LOG_RB], 1);
    __syncthreads();

    // B: block-wide exclusive scan of hist (1 bin/thread) + global reserve
    int sum = (t < NB) ? sm.b.hist[t] : 0;
    int lane = t & 63, wid = t >> 6;
    int v = sum;
    #pragma unroll
    for (int o = 1; o < 64; o <<= 1) {
        int u = __shfl_up(v, o);
        if (lane >= o) v += u;
    }
    if (lane == 63) sm.b.wsum[wid] = v;
    __syncthreads();
    if (t == 0) { int r = 0; for (int w = 0; w < 8; ++w) { sm.b.woff[w] = r; r += sm.b.wsum[w]; } }
    __syncthreads();
    int run = sm.b.woff[wid] + v - sum;
    if (t < NB) { sm.b.offs[t] = run; sm.b.cur[t] = run; }
    __syncthreads();
    if (t < NB)
        sm.b.gbase[t] = sm.b.hist[t] ? atomicAdd(&bin_cursor[t], sm.b.hist[t]) : 0;
    __syncthreads();

    // C: counting-sort into LDS staging (from registers)
    #pragma unroll
    for (int k = 0; k < 8; ++k) {
        if (ed[k] >= 0) {
            int b = ed[k] >> LOG_RB;
            int slot = atomicAdd(&sm.b.cur[b], 1);
            sm.b.staging[slot] = ((unsigned)(ed[k] & (RB - 1)) << SBITS) | (unsigned)es[k];
            sm.b.bin16[slot] = (unsigned short)b;
        }
    }
    __syncthreads();

    // D: coalesced write-out (runs of ~10.5 consecutive slots per bin)
    for (int i = t; i < n_valid; i += 512) {
        int b = sm.b.bin16[i];
        int pos = sm.b.gbase[b] + (i - sm.b.offs[b]);
        if (pos < CAPB) bins[(size_t)b * CAPB + pos] = sm.b.staging[i];
    }
}

// ---------------------------------------------------------------------------
// Accum: ONE 1024-thread block (16 waves) per 256-node bin (391 blocks).
// Segment register-cached in ONE global pass; LDS counting-sort into per-node
// order; then wave-per-node gather with 2-WAY UNROLL (two rec loads in
// flight -> MLP=2 against L2 latency): lane = e_off(0..7) x head(0..7);
// ONE 4B load per lane per edge; asrc/adst computed as FMAs from h; shuffle
// reduce; fused self-loop + normalize + bias + FC. No fp atomics anywhere.
// ---------------------------------------------------------------------------
__global__ __launch_bounds__(1024) void accum7_kernel(
    const unsigned* __restrict__ bins, const int* __restrict__ bin_cursor,
    const __half* __restrict__ rec,
    const float* __restrict__ att_src, const float* __restrict__ att_dst,
    const float* __restrict__ bias, const float* __restrict__ Wfc,
    const float* __restrict__ bfc, float* __restrict__ out)
{
    __shared__ unsigned staging[CAPB];          // 35.3 KB
    __shared__ int hist[RB], offs[RB + 1], cur[RB];

    int t = threadIdx.x;
    int b = blockIdx.x;
    int node0 = b * RB;

    if (t < RB) hist[t] = 0;
    __syncthreads();

    int cnt = bin_cursor[b];
    if (cnt > CAPB) cnt = CAPB;
    const unsigned* seg = bins + (size_t)b * CAPB;

    // cache segment in registers (single global pass)
    unsigned rcache[9];
    int nk = 0;
    for (int i = t; i < cnt; i += 1024) rcache[nk++] = seg[i];

    // A: per-node histogram
    for (int k = 0; k < nk; ++k)
        atomicAdd(&hist[rcache[k] >> SBITS], 1);
    __syncthreads();

    // B: scan of 256 counters by wave 0 (lane l owns nodes 4l..4l+3)
    if (t < 64) {
        int h0 = hist[4 * t], h1 = hist[4 * t + 1];
        int h2 = hist[4 * t + 2], h3 = hist[4 * t + 3];
        int v = h0 + h1 + h2 + h3;
        int inc = v;
        #pragma unroll
        for (int o = 1; o < 64; o <<= 1) {
            int u = __shfl_up(inc, o);
            if (t >= o) inc += u;
        }
        int ex = inc - v;
        offs[4 * t] = ex;     cur[4 * t] = ex;     ex += h0;
        offs[4 * t + 1] = ex; cur[4 * t + 1] = ex; ex += h1;
        offs[4 * t + 2] = ex; cur[4 * t + 2] = ex; ex += h2;
        offs[4 * t + 3] = ex; cur[4 * t + 3] = ex;
        if (t == 63) offs[RB] = inc;
    }
    __syncthreads();

    // C: sort src ids into per-node order in LDS
    for (int k = 0; k < nk; ++k) {
        unsigned r = rcache[k];
        int slot = atomicAdd(&cur[r >> SBITS], 1);
        staging[slot] = r & SMASK;
    }
    __syncthreads();

    // D: wave-per-node gather (16 waves x 16 nodes each), 2-way unrolled
    int wv = t >> 6, lane = t & 63;
    int h_id = lane & 7, e_off = lane >> 3;

    // lane constants: att coefficients (LOG2E folded), FC weights, biases
    float as0 = att_src[2 * h_id] * LOG2E, as1 = att_src[2 * h_id + 1] * LOG2E;
    float ad0 = att_dst[2 * h_id] * LOG2E, ad1 = att_dst[2 * h_id + 1] * LOG2E;
    float b0 = bias[2 * h_id], b1 = bias[2 * h_id + 1];
    float w00 = Wfc[(2 * h_id) * 2 + 0],     w01 = Wfc[(2 * h_id) * 2 + 1];
    float w10 = Wfc[(2 * h_id + 1) * 2 + 0], w11 = Wfc[(2 * h_id + 1) * 2 + 1];
    float c0 = bfc[0], c1 = bfc[1];

    for (int k = 0; k < RB / 16; ++k) {
        int ln = wv + 16 * k;           // wave-uniform local node
        int n = node0 + ln;
        if (n >= N_NODES) break;
        int st  = offs[ln];
        int deg = offs[ln + 1] - st;

        // this node's own h pair for this head (also used for self-loop)
        __half2 hn = *(const __half2*)(rec + (size_t)n * NF + 2 * h_id);
        float hn0 = __half2float(hn.x), hn1 = __half2float(hn.y);
        float adst_h = ad0 * hn0 + ad1 * hn1;

        float den = 0.f, num0 = 0.f, num1 = 0.f;
        float denB = 0.f, num0B = 0.f, num1B = 0.f;

        int i = e_off;
        for (; i + 8 < deg; i += 16) {
            int sA = staging[st + i];
            int sB = staging[st + i + 8];
            __half2 hsA = *(const __half2*)(rec + (size_t)sA * NF + 2 * h_id);
            __half2 hsB = *(const __half2*)(rec + (size_t)sB * NF + 2 * h_id);
            float hA0 = __half2float(hsA.x), hA1 = __half2float(hsA.y);
            float lA = fmaf(as0, hA0, fmaf(as1, hA1, adst_h));
            lA = lA > 0.f ? lA : NEG_SLOPE * lA;
            float pA = exp2f(lA);
            den += pA;
            num0 = fmaf(pA, hA0, num0);
            num1 = fmaf(pA, hA1, num1);
            float hB0 = __half2float(hsB.x), hB1 = __half2float(hsB.y);
            float lB = fmaf(as0, hB0, fmaf(as1, hB1, adst_h));
            lB = lB > 0.f ? lB : NEG_SLOPE * lB;
            float pB = exp2f(lB);
            denB += pB;
            num0B = fmaf(pB, hB0, num0B);
            num1B = fmaf(pB, hB1, num1B);
        }
        if (i < deg) {
            int s = staging[st + i];
            __half2 hs = *(const __half2*)(rec + (size_t)s * NF + 2 * h_id);
            float h0 = __half2float(hs.x), h1 = __half2float(hs.y);
            float l = fmaf(as0, h0, fmaf(as1, h1, adst_h));
            l = l > 0.f ? l : NEG_SLOPE * l;
            float p = exp2f(l);
            den += p;
            num0 = fmaf(p, h0, num0);
            num1 = fmaf(p, h1, num1);
        }
        den += denB; num0 += num0B; num1 += num1B;

        #pragma unroll
        for (int m = 8; m < 64; m <<= 1) {
            den  += __shfl_xor(den,  m);
            num0 += __shfl_xor(num0, m);
            num1 += __shfl_xor(num1, m);
        }
        // self-loop folded analytically
        {
            float l = fmaf(as0, hn0, fmaf(as1, hn1, adst_h));
            l = l > 0.f ? l : NEG_SLOPE * l;
            float p = exp2f(l);
            den += p;
            num0 = fmaf(p, hn0, num0);
            num1 = fmaf(p, hn1, num1);
        }
        // normalize + bias + FC, sum over heads
        float g0 = num0 / den + b0;
        float g1 = num1 / den + b1;
        float o0 = g0 * w00 + g1 * w10;
        float o1 = g0 * w01 + g1 * w11;
        #pragma unroll
        for (int m = 1; m < 8; m <<= 1) {
            o0 += __shfl_xor(o0, m);
            o1 += __shfl_xor(o1, m);
        }
        if (lane == 0) {
            float2 res = { o0 + c0, o1 + c1 };
            *(float2*)(out + (size_t)n * 2) = res;
        }
    }
}

// ---------------------------------------------------------------------------
extern "C" void kernel_launch(void* const* d_in, const int* in_sizes, int n_in,
                              void* d_out, int out_size, void* d_ws, size_t ws_size,
                              hipStream_t stream)
{
    const float* x       = (const float*)d_in[0];
    const int*   ei      = (const int*)d_in[1];   // [2, E]
    const float* W       = (const float*)d_in[3];
    const float* att_src = (const float*)d_in[4];
    const float* att_dst = (const float*)d_in[5];
    const float* bias    = (const float*)d_in[6];
    const float* Wfc     = (const float*)d_in[7];
    const float* bfc     = (const float*)d_in[8];
    float*       out     = (float*)d_out;

    const int E  = in_sizes[1] / 2;
    const int SB = (E + BIN_C - 1) / BIN_C;            // bin-role blocks (782)
    const int PB = (N_NODES * 8 + 511) / 512;          // phase1-role blocks (1563)

    // ws layout: rec f16[N*16] (3.2MB) | bin_cursor i32[NB] | (4KB align) |
    //            bins u32[NB*CAPB] (~14.1MB)
    __half* rec        = (__half*)d_ws;
    int*    bin_cursor = (int*)((char*)d_ws + (size_t)N_NODES * NF * 2);
    size_t  bins_off   = (((size_t)((char*)bin_cursor - (char*)d_ws)) + NB * 4 + 4095) & ~(size_t)4095;
    unsigned* bins     = (unsigned*)((char*)d_ws + bins_off);

    hipMemsetAsync(bin_cursor, 0, NB * sizeof(int), stream);

    fused_p1_bin<<<SB + PB, 512, 0, stream>>>(
        ei, bin_cursor, bins, x, W, rec, E, SB);
    accum7_kernel<<<NB, 1024, 0, stream>>>(
        bins, bin_cursor, rec, att_src, att_dst, bias, Wfc, bfc, out);
}